// Round 9
// baseline (120.980 us; speedup 1.0000x reference)
//
#include <hip/hip_runtime.h>
#include <hip/hip_bf16.h>
#include <cmath>

using short8  = __attribute__((ext_vector_type(8))) short;
using f32x4   = __attribute__((ext_vector_type(4))) float;
using uint4v  = __attribute__((ext_vector_type(4))) unsigned;

#define DEV static __device__ __forceinline__

DEV unsigned short f2bf(float f) {
  union { float f; unsigned u; } v; v.f = f;
  unsigned r = v.u + 0x7FFFu + ((v.u >> 16) & 1u);
  return (unsigned short)(r >> 16);
}
DEV float bf2f(unsigned short b) {
  union { unsigned u; float f; } v; v.u = ((unsigned)b) << 16;
  return v.f;
}

DEV void async_copy16(const void* g, void* l) {
  __builtin_amdgcn_global_load_lds(
      (const __attribute__((address_space(1))) void*)g,
      (__attribute__((address_space(3))) void*)l, 16, 0, 0);
}

// DPP helpers: row_ror:N within 16-lane rows (VALU pipe, no LDS)
#define DPPF(x, ctrl)                                                     \
  __builtin_bit_cast(float, __builtin_amdgcn_update_dpp(                  \
      __builtin_bit_cast(int, (x)), __builtin_bit_cast(int, (x)), (ctrl), \
      0xF, 0xF, false))

DEV float rowmax16(float t) {
  t = fmaxf(t, DPPF(t, 0x128));
  t = fmaxf(t, DPPF(t, 0x124));
  t = fmaxf(t, DPPF(t, 0x122));
  t = fmaxf(t, DPPF(t, 0x121));
  return t;
}
DEV float rowsum16(float t) {
  t += DPPF(t, 0x128);
  t += DPPF(t, 0x124);
  t += DPPF(t, 0x122);
  t += DPPF(t, 0x121);
  return t;
}
DEV unsigned dpp_xor8(unsigned x) {  // lane^8 within each 16-lane row
  return (unsigned)__builtin_amdgcn_update_dpp((int)x, (int)x, 0x128, 0xF, 0xF, false);
}

// ---------------- fused prep: f32->bf16 converts + PE table + bias pack ----
__global__ __launch_bounds__(256) void prep_kernel(
    const float* __restrict__ x,  const float* __restrict__ Wq,
    const float* __restrict__ Wk, const float* __restrict__ Wv,
    const float* __restrict__ Wp, const float* __restrict__ Wo,
    const float* __restrict__ bq, const float* __restrict__ bk,
    const float* __restrict__ bv,
    unsigned short* __restrict__ xb, unsigned short* __restrict__ Wqkvb,
    unsigned short* __restrict__ Wpb, unsigned short* __restrict__ Wob,
    unsigned short* __restrict__ peb, float* __restrict__ bqkv) {
  const int blk = blockIdx.x;
  const int tid = threadIdx.x;
  if (blk < 9216) {  // converts
    const float* src;
    unsigned short* dst;
    int i;
    if (blk < 4096) {
      src = x; dst = xb; i = blk * 256 + tid;
    } else {
      const int w = (blk - 4096) >> 10;
      i = ((blk - 4096) & 1023) * 256 + tid;
      if      (w == 0) { src = Wq; dst = Wqkvb; }
      else if (w == 1) { src = Wk; dst = Wqkvb + 1048576; }
      else if (w == 2) { src = Wv; dst = Wqkvb + 2097152; }
      else if (w == 3) { src = Wp; dst = Wpb; }
      else             { src = Wo; dst = Wob; }
    }
    float4 v = ((const float4*)src)[i];
    ushort4 o;
    o.x = f2bf(v.x); o.y = f2bf(v.y); o.z = f2bf(v.z); o.w = f2bf(v.w);
    ((ushort4*)dst)[i] = o;
  } else if (blk < 11264) {  // PE table
    const int idx = (blk - 9216) * 256 + tid;
    const int r = idx >> 9;
    const int m = idx & 511;
    const float inv_freq = __expf((float)m * -0.017988946039016004f);
    const float ang = (float)(511 - r) * inv_freq;
    peb[(size_t)r * 1024 + 2 * m]     = f2bf(sinf(ang));
    peb[(size_t)r * 1024 + 2 * m + 1] = f2bf(cosf(ang));
  } else {  // bias pack
    const int i = (blk - 11264) * 256 + tid;
    const float* s = (i < 1024) ? bq : (i < 2048) ? bk : bv;
    bqkv[i] = s[i & 1023];
  }
}

// ---------------- GEMM tile body: C[M,N] = A[M,K] @ B[N,K]^T + bias[N] -----
template <int OUTF32>
DEV void gemm_tile(const unsigned short* __restrict__ A,
                   const unsigned short* __restrict__ B,
                   const float* __restrict__ bias, void* __restrict__ Cout,
                   int N, int K, int m0, int n0, int tid,
                   unsigned short* sA, unsigned short* sB) {
  const int lane = tid & 63;
  const int wave = tid >> 6;

  const unsigned short* gA[4];
  const unsigned short* gB[4];
  unsigned ldst[4];
#pragma unroll
  for (int it = 0; it < 4; ++it) {
    unsigned o = (unsigned)(it * 4096 + wave * 1024 + lane * 16);
    unsigned row = o >> 7;
    unsigned x = (o & 127u) ^ ((row & 7u) << 4);
    ldst[it] = it * 4096 + wave * 1024;
    gA[it] = A + (size_t)(m0 + (int)row) * K + (x >> 1);
    gB[it] = B + (size_t)(n0 + (int)row) * K + (x >> 1);
  }

  f32x4 acc[4][4];
#pragma unroll
  for (int i = 0; i < 4; ++i)
#pragma unroll
    for (int j = 0; j < 4; ++j) acc[i][j] = f32x4{0.f, 0.f, 0.f, 0.f};

  const int wm = (wave >> 1) << 6;
  const int wn = (wave & 1) << 6;
  const int rsel = lane & 15;
  const int ksel = (lane >> 4) << 4;

  for (int k0 = 0; k0 < K; k0 += 64) {
#pragma unroll
    for (int it = 0; it < 4; ++it) {
      async_copy16(gA[it] + k0, (char*)sA + ldst[it]);
      async_copy16(gB[it] + k0, (char*)sB + ldst[it]);
    }
    __syncthreads();
#pragma unroll
    for (int kb = 0; kb < 2; ++kb) {
      const int kbyte = kb * 64 + ksel;
      short8 af[4], bf8[4];
#pragma unroll
      for (int i = 0; i < 4; ++i) {
        const int ra = wm + i * 16 + rsel;
        af[i] = *(const short8*)((const char*)sA + ra * 128 + (kbyte ^ ((ra & 7) << 4)));
        const int rb = wn + i * 16 + rsel;
        bf8[i] = *(const short8*)((const char*)sB + rb * 128 + (kbyte ^ ((rb & 7) << 4)));
      }
#pragma unroll
      for (int i = 0; i < 4; ++i)
#pragma unroll
        for (int j = 0; j < 4; ++j)
          acc[i][j] = __builtin_amdgcn_mfma_f32_16x16x32_bf16(af[i], bf8[j], acc[i][j], 0, 0, 0);
    }
    __syncthreads();
  }

#pragma unroll
  for (int i = 0; i < 4; ++i) {
    const int row0 = m0 + wm + i * 16 + ((lane >> 4) << 2);
#pragma unroll
    for (int j = 0; j < 4; ++j) {
      const int col = n0 + wn + j * 16 + rsel;
      const float bb = bias[col];
#pragma unroll
      for (int r = 0; r < 4; ++r) {
        const float val = acc[i][j][r] + bb;
        if (OUTF32)
          ((float*)Cout)[(size_t)(row0 + r) * N + col] = val;
        else
          ((unsigned short*)Cout)[(size_t)(row0 + r) * N + col] = f2bf(val);
      }
    }
  }
}

// fused QKV-projection + E-projection GEMM (832 blocks: 768 QKV + 64 E)
__global__ __launch_bounds__(256) void gemm_qkv_e_kernel(
    const unsigned short* __restrict__ xb, const unsigned short* __restrict__ Wqkvb,
    const float* __restrict__ bqkv, unsigned short* __restrict__ QKVb,
    const unsigned short* __restrict__ peb, const unsigned short* __restrict__ Wpb,
    const float* __restrict__ bp, unsigned short* __restrict__ Eb) {
  __shared__ unsigned short sA[128 * 64];
  __shared__ unsigned short sB[128 * 64];
  const int cpx = 104;  // 832/8
  const int bid = (blockIdx.x & 7) * cpx + (blockIdx.x >> 3);
  if (bid < 768) {
    const int mt = bid / 24, nt = bid - mt * 24;
    gemm_tile<0>(xb, Wqkvb, bqkv, QKVb, 3072, 1024, mt << 7, nt << 7,
                 threadIdx.x, sA, sB);
  } else {
    const int b2 = bid - 768;
    gemm_tile<0>(peb, Wpb, bp, Eb, 1024, 1024, (b2 >> 3) << 7, (b2 & 7) << 7,
                 threadIdx.x, sA, sB);
  }
}

// output projection (256 blocks)
__global__ __launch_bounds__(256) void gemm_out_kernel(
    const unsigned short* __restrict__ Ob, const unsigned short* __restrict__ Wob,
    const float* __restrict__ bo, float* __restrict__ out) {
  __shared__ unsigned short sA[128 * 64];
  __shared__ unsigned short sB[128 * 64];
  const int cpx = 32;  // 256/8
  const int bid = (blockIdx.x & 7) * cpx + (blockIdx.x >> 3);
  gemm_tile<1>(Ob, Wob, bo, out, 1024, 1024, (bid >> 3) << 7, (bid & 7) << 7,
               threadIdx.x, sA, sB);
}

// ---------------- fused rel-pos flash attention ----------------
// 512 blocks (XCD-swizzled) x 4 waves; 32 q-rows/wave (two 16-row i-frags),
// 128 q-rows/block; KVBLK=64; ONE barrier/kt. K dbuf, E ring-4 (192-row live
// window), Vt dbuf, V regs two tiles ahead. K/V/E-band LDS reads are shared
// by both i-frags (per-q-row LDS ops -40% vs 16-row waves — the round-8
// bottleneck). DPP reductions/transpose; bpermute only for skew gather.
// LDS = 80KB -> 2 blocks/CU. ~210 VGPR -> launch_bounds(256,2), no spill.
__global__ __launch_bounds__(256, 2) void attn_kernel(
    const unsigned short* __restrict__ QKV,  // (4096, 3072): Q|K|V
    const unsigned short* __restrict__ E,    // (1024, 1024)
    const float* __restrict__ uvec, const float* __restrict__ vvec,
    unsigned short* __restrict__ O) {        // (4096, 1024)
  __shared__ unsigned short sK[2 * 4096];
  __shared__ unsigned short sE[4 * 4096];
  __shared__ unsigned short sVt[2 * 4096];
  __shared__ unsigned short sP[4][2048];

  const int tid = threadIdx.x;
  const int lane = tid & 63;
  const int wave = tid >> 6;   // 0..3
  const int cpx = gridDim.x >> 3;
  const int bid = (blockIdx.x & 7) * cpx + (blockIdx.x >> 3);
  const int qt = bid & 3;
  const int h = (bid >> 2) & 15;
  const int b = bid >> 6;
  const int q0 = qt << 7;

  const int rsel = lane & 15;
  const int g = lane >> 4;
  const int ilocb = g << 2;
  const int cb0 = 96 - 32 * wave;  // union E-band start (96 cols, 6 frags)

  const unsigned short* Qb = QKV + (size_t)b * 512 * 3072 + h * 64;
  const unsigned short* Kb = Qb + 1024;
  const unsigned short* Vb = Qb + 2048;

  const float sc = 0.125f * 1.44269504088896f;  // 1/sqrt(dh) * log2(e)

  // ---- V(0) regs first ----
  short8 v8b[2];
#pragma unroll
  for (int it = 0; it < 2; ++it) {
    const int c = it * 256 + tid;
    v8b[it] = *(const short8*)(Vb + (size_t)(c >> 3) * 3072 + ((c & 7) << 3));
  }
  // K(0) via global_load_lds
#pragma unroll
  for (int it = 0; it < 2; ++it) {
    const unsigned o = (unsigned)(it * 4096 + wave * 1024 + lane * 16);
    const unsigned row = o >> 7;
    const unsigned x = (o & 127u) ^ ((row & 7u) << 4);
    async_copy16(Kb + (size_t)row * 3072 + (x >> 1),
                 (char*)sK + it * 4096 + wave * 1024);
  }
  // E window halves H = 6-2qt .. 8-2qt into ring slots H&3
#pragma unroll
  for (int hh = 0; hh < 3; ++hh) {
    const int H = 6 - 2 * qt + hh;
#pragma unroll
    for (int it = 0; it < 2; ++it) {
      const unsigned o = (unsigned)(it * 4096 + wave * 1024 + lane * 16);
      const unsigned row = o >> 7;
      const unsigned x = (o & 127u) ^ ((row & 7u) << 4);
      async_copy16(E + (size_t)(H * 64 + (int)row) * 1024 + h * 64 + (x >> 1),
                   (char*)sE + (H & 3) * 8192 + it * 4096 + wave * 1024);
    }
  }

  // ---- Q fragments (A-layout) for both i-frags, pre-scaled ----
  short8 aU[2][2], aV[2][2];
#pragma unroll
  for (int f = 0; f < 2; ++f) {
    const int qrow = q0 + 32 * wave + 16 * f + rsel;
    const int dob = g * 8;
#pragma unroll
    for (int kb = 0; kb < 2; ++kb) {
      short8 q8 = *(const short8*)(Qb + (size_t)qrow * 3072 + kb * 32 + dob);
#pragma unroll
      for (int j = 0; j < 8; ++j) {
        const float qf = bf2f((unsigned short)q8[j]);
        aU[f][kb][j] = (short)f2bf((qf + uvec[h * 64 + kb * 32 + dob + j]) * sc);
        aV[f][kb][j] = (short)f2bf((qf + vvec[h * 64 + kb * 32 + dob + j]) * sc);
      }
    }
  }

  // transpose V(0) -> Vt[0] (DPP lane^8 exchange, b32 writes)
#pragma unroll
  for (int it = 0; it < 2; ++it) {
    const int c = it * 256 + tid;
    const int trow = c >> 3;
    const int db = (c & 7) << 3;
    const int odd = trow & 1;
    const int kp = (trow & ~1) * 2;
    const uint4v dw = __builtin_bit_cast(uint4v, v8b[it]);
#pragma unroll
    for (int p = 0; p < 4; ++p) {
      const unsigned mine = dw[p];
      const unsigned other = dpp_xor8(mine);
      const unsigned res = odd ? ((mine & 0xffff0000u) | (other >> 16))
                               : ((other << 16) | (mine & 0xffffu));
      const int d = db + 2 * p + odd;
      *(unsigned*)((char*)sVt + d * 128 + (kp ^ (((d ^ (d >> 3)) & 7) << 4))) = res;
    }
  }
  // V(1) -> regs
#pragma unroll
  for (int it = 0; it < 2; ++it) {
    const int c = it * 256 + tid;
    v8b[it] = *(const short8*)(Vb + (size_t)(64 + (c >> 3)) * 3072 + ((c & 7) << 3));
  }

  // skew-gather shuffle constants (kt- and f-invariant)
  int srcLn[4];
  bool hiSel[4];
#pragma unroll
  for (int r = 0; r < 4; ++r) {
    const int offs = 15 - (ilocb + r) + rsel;  // 0..30
    srcLn[r] = (lane & 48) | (offs & 15);
    hiSel[r] = offs >= 16;
  }

  float mrun[2][4], lrun[2][4];
  f32x4 oacc[2][4];
#pragma unroll
  for (int f = 0; f < 2; ++f)
#pragma unroll
    for (int r = 0; r < 4; ++r) { mrun[f][r] = -INFINITY; lrun[f][r] = 0.f; }
#pragma unroll
  for (int f = 0; f < 2; ++f)
#pragma unroll
    for (int n = 0; n < 4; ++n) oacc[f][n] = f32x4{0.f, 0.f, 0.f, 0.f};

  for (int kt = 0; kt < 8; ++kt) {
    const int k0 = kt << 6;
    const int cur = kt & 1;
    const int H0 = 6 - 2 * qt + kt;  // window low half index

    __syncthreads();  // single barrier: drains prefetched glds

    if (kt < 7) {
      const int kn = k0 + 64;
      // K(kt+1) -> sK[cur^1]
#pragma unroll
      for (int it = 0; it < 2; ++it) {
        const unsigned o = (unsigned)(it * 4096 + wave * 1024 + lane * 16);
        const unsigned row = o >> 7;
        const unsigned x = (o & 127u) ^ ((row & 7u) << 4);
        async_copy16(Kb + (size_t)(kn + (int)row) * 3072 + (x >> 1),
                     (char*)sK + (cur ^ 1) * 8192 + it * 4096 + wave * 1024);
      }
      // E half H0+3 -> ring slot (H0+3)&3
      {
        const int H = H0 + 3;
#pragma unroll
        for (int it = 0; it < 2; ++it) {
          const unsigned o = (unsigned)(it * 4096 + wave * 1024 + lane * 16);
          const unsigned row = o >> 7;
          const unsigned x = (o & 127u) ^ ((row & 7u) << 4);
          async_copy16(E + (size_t)(H * 64 + (int)row) * 1024 + h * 64 + (x >> 1),
                       (char*)sE + (H & 3) * 8192 + it * 4096 + wave * 1024);
        }
      }
      // transpose V(kt+1) (in v8b) -> Vt[cur^1]
#pragma unroll
      for (int it = 0; it < 2; ++it) {
        const int c = it * 256 + tid;
        const int trow = c >> 3;
        const int db = (c & 7) << 3;
        const int odd = trow & 1;
        const int kp = (trow & ~1) * 2;
        const uint4v dw = __builtin_bit_cast(uint4v, v8b[it]);
#pragma unroll
        for (int p = 0; p < 4; ++p) {
          const unsigned mine = dw[p];
          const unsigned other = dpp_xor8(mine);
          const unsigned res = odd ? ((mine & 0xffff0000u) | (other >> 16))
                                   : ((other << 16) | (mine & 0xffffu));
          const int d = db + 2 * p + odd;
          *(unsigned*)((char*)sVt + (cur ^ 1) * 8192 + d * 128 +
                       (kp ^ (((d ^ (d >> 3)) & 7) << 4))) = res;
        }
      }
      // V(kt+2) -> regs
      if (kt < 6) {
#pragma unroll
        for (int it = 0; it < 2; ++it) {
          const int c = it * 256 + tid;
          v8b[it] = *(const short8*)(Vb + (size_t)(kn + 64 + (c >> 3)) * 3072 +
                                     ((c & 7) << 3));
        }
      }
    }

    // SK = Qu@K^T (2 x 16x64) ; G = Qv@Ewin^T (2 x 16x80, shared band reads)
    f32x4 skacc[2][4], gacc[2][5];
#pragma unroll
    for (int f = 0; f < 2; ++f) {
#pragma unroll
      for (int nf = 0; nf < 4; ++nf) skacc[f][nf] = f32x4{0.f, 0.f, 0.f, 0.f};
#pragma unroll
      for (int cf = 0; cf < 5; ++cf) gacc[f][cf] = f32x4{0.f, 0.f, 0.f, 0.f};
    }
    __builtin_amdgcn_s_setprio(1);
#pragma unroll
    for (int kb = 0; kb < 2; ++kb) {
      const int kbyte = kb * 64 + g * 16;
      // K fragments (shared by both i-frags)
      short8 kb8[4];
#pragma unroll
      for (int nf = 0; nf < 4; ++nf) {
        const int rb = nf * 16 + rsel;
        kb8[nf] = *(const short8*)((const char*)sK + cur * 8192 + rb * 128 +
                                   (kbyte ^ ((rb & 7) << 4)));
      }
#pragma unroll
      for (int f = 0; f < 2; ++f)
#pragma unroll
        for (int nf = 0; nf < 4; ++nf)
          skacc[f][nf] = __builtin_amdgcn_mfma_f32_16x16x32_bf16(
              aU[f][kb], kb8[nf], skacc[f][nf], 0, 0, 0);
      // E union band fragments (6, shared)
      short8 eb8[6];
#pragma unroll
      for (int cfu = 0; cfu < 6; ++cfu) {
        const int rowbase = cb0 + 16 * cfu;
        const int rb = rowbase + rsel;
        const int slot = (H0 + (rowbase >> 6)) & 3;
        eb8[cfu] = *(const short8*)((const char*)sE + slot * 8192 +
                                    (rb & 63) * 128 + (kbyte ^ ((rb & 7) << 4)));
      }
#pragma unroll
      for (int f = 0; f < 2; ++f)
#pragma unroll
        for (int j = 0; j < 5; ++j)
          gacc[f][j] = __builtin_amdgcn_mfma_f32_16x16x32_bf16(
              aV[f][kb], eb8[j + 1 - f], gacc[f][j], 0, 0, 0);
    }
    __builtin_amdgcn_s_setprio(0);

    // diag-gather G via bpermute: S[f][i,j] += G[f][i, 15-i+j(+band)]
#pragma unroll
    for (int f = 0; f < 2; ++f)
#pragma unroll
      for (int r = 0; r < 4; ++r) {
        float gsh[5];
#pragma unroll
        for (int cf = 0; cf < 5; ++cf)
          gsh[cf] = __shfl(gacc[f][cf][r], srcLn[r], 64);
#pragma unroll
        for (int nf = 0; nf < 4; ++nf)
          skacc[f][nf][r] += hiSel[r] ? gsh[nf + 1] : gsh[nf];
      }

    // online softmax in exp2 domain; reductions via DPP (VALU)
    float scl[2][4];
#pragma unroll
    for (int f = 0; f < 2; ++f) {
      float rsum[4];
#pragma unroll
      for (int r = 0; r < 4; ++r) {
        float t = fmaxf(fmaxf(skacc[f][0][r], skacc[f][1][r]),
                        fmaxf(skacc[f][2][r], skacc[f][3][r]));
        t = rowmax16(t);
        const float mnew = fmaxf(mrun[f][r], t);
        scl[f][r] = __builtin_amdgcn_exp2f(mrun[f][r] - mnew);
        mrun[f][r] = mnew;
        rsum[r] = 0.f;
      }
#pragma unroll
      for (int nf = 0; nf < 4; ++nf)
#pragma unroll
        for (int r = 0; r < 4; ++r) {
          const float p = __builtin_amdgcn_exp2f(skacc[f][nf][r] - mrun[f][r]);
          rsum[r] += p;
          const int rloc = 16 * f + ilocb + r;
          const int jb = (nf * 16 + rsel) * 2;
          *(unsigned short*)((char*)sP[wave] + rloc * 128 +
                             (jb ^ ((rloc & 7) << 4))) = f2bf(p);
        }
#pragma unroll
      for (int r = 0; r < 4; ++r)
        lrun[f][r] = lrun[f][r] * scl[f][r] + rowsum16(rsum[r]);
#pragma unroll
      for (int nf = 0; nf < 4; ++nf)
#pragma unroll
        for (int r = 0; r < 4; ++r) oacc[f][nf][r] *= scl[f][r];
    }

    // O += P@V : A-frags per i-frag from sP, B-frags shared from sVt[cur]
    __builtin_amdgcn_s_setprio(1);
#pragma unroll
    for (int kb = 0; kb < 2; ++kb) {
      const int kbyte = kb * 64 + g * 16;
      short8 ap[2];
#pragma unroll
      for (int f = 0; f < 2; ++f) {
        const int pr = 16 * f + rsel;
        ap[f] = *(const short8*)((const char*)sP[wave] + pr * 128 +
                                 (kbyte ^ ((pr & 7) << 4)));
      }
#pragma unroll
      for (int nf = 0; nf < 4; ++nf) {
        const int rv = nf * 16 + rsel;
        short8 vb8 = *(const short8*)((const char*)sVt + cur * 8192 + rv * 128 +
                                      (kbyte ^ (((rv ^ (rv >> 3)) & 7) << 4)));
#pragma unroll
        for (int f = 0; f < 2; ++f)
          oacc[f][nf] = __builtin_amdgcn_mfma_f32_16x16x32_bf16(
              ap[f], vb8, oacc[f][nf], 0, 0, 0);
      }
    }
    __builtin_amdgcn_s_setprio(0);
  }

  // epilogue
#pragma unroll
  for (int f = 0; f < 2; ++f)
#pragma unroll
    for (int nf = 0; nf < 4; ++nf)
#pragma unroll
      for (int r = 0; r < 4; ++r) {
        const int t = q0 + 32 * wave + 16 * f + ilocb + r;
        const int col = h * 64 + nf * 16 + rsel;
        O[(size_t)(b * 512 + t) * 1024 + col] = f2bf(oacc[f][nf][r] / lrun[f][r]);
      }
}

// ---------------- launch ----------------
extern "C" void kernel_launch(void* const* d_in, const int* in_sizes, int n_in,
                              void* d_out, int out_size, void* d_ws, size_t ws_size,
                              hipStream_t stream) {
  const float* x  = (const float*)d_in[0];
  const float* Wq = (const float*)d_in[1];
  const float* bq = (const float*)d_in[2];
  const float* Wk = (const float*)d_in[3];
  const float* bk = (const float*)d_in[4];
  const float* Wv = (const float*)d_in[5];
  const float* bv = (const float*)d_in[6];
  const float* Wp = (const float*)d_in[7];
  const float* bp = (const float*)d_in[8];
  const float* Wo = (const float*)d_in[9];
  const float* bo = (const float*)d_in[10];
  const float* u  = (const float*)d_in[11];
  const float* v  = (const float*)d_in[12];
  float* out = (float*)d_out;

  char* ws = (char*)d_ws;
  const size_t MB = 1024 * 1024;
  unsigned short* xb    = (unsigned short*)(ws);             // 4096x1024 bf16
  unsigned short* Wqkvb = (unsigned short*)(ws + 8 * MB);    // 3072x1024
  unsigned short* Wpb   = (unsigned short*)(ws + 14 * MB);   // 1024x1024
  unsigned short* Wob   = (unsigned short*)(ws + 16 * MB);   // 1024x1024
  unsigned short* peb   = (unsigned short*)(ws + 18 * MB);   // 1024x1024
  unsigned short* QKVb  = (unsigned short*)(ws + 20 * MB);   // 4096x3072
  unsigned short* Eb    = (unsigned short*)(ws + 44 * MB);   // 1024x1024
  unsigned short* Ob    = (unsigned short*)(ws + 46 * MB);   // 4096x1024
  float* bqkv           = (float*)(ws + 54 * MB);            // 3072 f32

  prep_kernel<<<dim3(11276), dim3(256), 0, stream>>>(
      x, Wq, Wk, Wv, Wp, Wo, bq, bk, bv, xb, Wqkvb, Wpb, Wob, peb, bqkv);

  gemm_qkv_e_kernel<<<dim3(832), dim3(256), 0, stream>>>(
      xb, Wqkvb, bqkv, QKVb, peb, Wpb, bp, Eb);
  attn_kernel<<<dim3(512), dim3(256), 0, stream>>>(QKVb, Eb, u, v, Ob);
  gemm_out_kernel<<<dim3(256), dim3(256), 0, stream>>>(Ob, Wob, bo, out);
}

// Round 10
// 119.126 us; speedup vs baseline: 1.0156x; 1.0156x over previous
//
#include <hip/hip_runtime.h>
#include <hip/hip_bf16.h>
#include <cmath>

using short8  = __attribute__((ext_vector_type(8))) short;
using f32x4   = __attribute__((ext_vector_type(4))) float;
using uint4v  = __attribute__((ext_vector_type(4))) unsigned;

#define DEV static __device__ __forceinline__

DEV unsigned short f2bf(float f) {
  union { float f; unsigned u; } v; v.f = f;
  unsigned r = v.u + 0x7FFFu + ((v.u >> 16) & 1u);
  return (unsigned short)(r >> 16);
}
DEV float bf2f(unsigned short b) {
  union { unsigned u; float f; } v; v.u = ((unsigned)b) << 16;
  return v.f;
}

DEV void async_copy16(const void* g, void* l) {
  __builtin_amdgcn_global_load_lds(
      (const __attribute__((address_space(1))) void*)g,
      (__attribute__((address_space(3))) void*)l, 16, 0, 0);
}

// DPP helpers: row_ror:N within 16-lane rows (VALU pipe, no LDS)
#define DPPF(x, ctrl)                                                     \
  __builtin_bit_cast(float, __builtin_amdgcn_update_dpp(                  \
      __builtin_bit_cast(int, (x)), __builtin_bit_cast(int, (x)), (ctrl), \
      0xF, 0xF, false))

DEV float rowmax16(float t) {
  t = fmaxf(t, DPPF(t, 0x128));
  t = fmaxf(t, DPPF(t, 0x124));
  t = fmaxf(t, DPPF(t, 0x122));
  t = fmaxf(t, DPPF(t, 0x121));
  return t;
}
DEV float rowsum16(float t) {
  t += DPPF(t, 0x128);
  t += DPPF(t, 0x124);
  t += DPPF(t, 0x122);
  t += DPPF(t, 0x121);
  return t;
}
DEV unsigned dpp_xor8(unsigned x) {  // lane^8 within each 16-lane row
  return (unsigned)__builtin_amdgcn_update_dpp((int)x, (int)x, 0x128, 0xF, 0xF, false);
}

// ---------------- fused prep: f32->bf16 converts + PE table + bias pack ----
__global__ __launch_bounds__(256) void prep_kernel(
    const float* __restrict__ x,  const float* __restrict__ Wq,
    const float* __restrict__ Wk, const float* __restrict__ Wv,
    const float* __restrict__ Wp, const float* __restrict__ Wo,
    const float* __restrict__ bq, const float* __restrict__ bk,
    const float* __restrict__ bv,
    unsigned short* __restrict__ xb, unsigned short* __restrict__ Wqkvb,
    unsigned short* __restrict__ Wpb, unsigned short* __restrict__ Wob,
    unsigned short* __restrict__ peb, float* __restrict__ bqkv) {
  const int blk = blockIdx.x;
  const int tid = threadIdx.x;
  if (blk < 9216) {  // converts
    const float* src;
    unsigned short* dst;
    int i;
    if (blk < 4096) {
      src = x; dst = xb; i = blk * 256 + tid;
    } else {
      const int w = (blk - 4096) >> 10;
      i = ((blk - 4096) & 1023) * 256 + tid;
      if      (w == 0) { src = Wq; dst = Wqkvb; }
      else if (w == 1) { src = Wk; dst = Wqkvb + 1048576; }
      else if (w == 2) { src = Wv; dst = Wqkvb + 2097152; }
      else if (w == 3) { src = Wp; dst = Wpb; }
      else             { src = Wo; dst = Wob; }
    }
    float4 v = ((const float4*)src)[i];
    ushort4 o;
    o.x = f2bf(v.x); o.y = f2bf(v.y); o.z = f2bf(v.z); o.w = f2bf(v.w);
    ((ushort4*)dst)[i] = o;
  } else if (blk < 11264) {  // PE table
    const int idx = (blk - 9216) * 256 + tid;
    const int r = idx >> 9;
    const int m = idx & 511;
    const float inv_freq = __expf((float)m * -0.017988946039016004f);
    const float ang = (float)(511 - r) * inv_freq;
    peb[(size_t)r * 1024 + 2 * m]     = f2bf(sinf(ang));
    peb[(size_t)r * 1024 + 2 * m + 1] = f2bf(cosf(ang));
  } else {  // bias pack
    const int i = (blk - 11264) * 256 + tid;
    const float* s = (i < 1024) ? bq : (i < 2048) ? bk : bv;
    bqkv[i] = s[i & 1023];
  }
}

// ---------------- GEMM tile body: C[M,N] = A[M,K] @ B[N,K]^T + bias[N] -----
template <int OUTF32>
DEV void gemm_tile(const unsigned short* __restrict__ A,
                   const unsigned short* __restrict__ B,
                   const float* __restrict__ bias, void* __restrict__ Cout,
                   int N, int K, int m0, int n0, int tid,
                   unsigned short* sA, unsigned short* sB) {
  const int lane = tid & 63;
  const int wave = tid >> 6;

  const unsigned short* gA[4];
  const unsigned short* gB[4];
  unsigned ldst[4];
#pragma unroll
  for (int it = 0; it < 4; ++it) {
    unsigned o = (unsigned)(it * 4096 + wave * 1024 + lane * 16);
    unsigned row = o >> 7;
    unsigned x = (o & 127u) ^ ((row & 7u) << 4);
    ldst[it] = it * 4096 + wave * 1024;
    gA[it] = A + (size_t)(m0 + (int)row) * K + (x >> 1);
    gB[it] = B + (size_t)(n0 + (int)row) * K + (x >> 1);
  }

  f32x4 acc[4][4];
#pragma unroll
  for (int i = 0; i < 4; ++i)
#pragma unroll
    for (int j = 0; j < 4; ++j) acc[i][j] = f32x4{0.f, 0.f, 0.f, 0.f};

  const int wm = (wave >> 1) << 6;
  const int wn = (wave & 1) << 6;
  const int rsel = lane & 15;
  const int ksel = (lane >> 4) << 4;

  for (int k0 = 0; k0 < K; k0 += 64) {
#pragma unroll
    for (int it = 0; it < 4; ++it) {
      async_copy16(gA[it] + k0, (char*)sA + ldst[it]);
      async_copy16(gB[it] + k0, (char*)sB + ldst[it]);
    }
    __syncthreads();
#pragma unroll
    for (int kb = 0; kb < 2; ++kb) {
      const int kbyte = kb * 64 + ksel;
      short8 af[4], bf8[4];
#pragma unroll
      for (int i = 0; i < 4; ++i) {
        const int ra = wm + i * 16 + rsel;
        af[i] = *(const short8*)((const char*)sA + ra * 128 + (kbyte ^ ((ra & 7) << 4)));
        const int rb = wn + i * 16 + rsel;
        bf8[i] = *(const short8*)((const char*)sB + rb * 128 + (kbyte ^ ((rb & 7) << 4)));
      }
#pragma unroll
      for (int i = 0; i < 4; ++i)
#pragma unroll
        for (int j = 0; j < 4; ++j)
          acc[i][j] = __builtin_amdgcn_mfma_f32_16x16x32_bf16(af[i], bf8[j], acc[i][j], 0, 0, 0);
    }
    __syncthreads();
  }

#pragma unroll
  for (int i = 0; i < 4; ++i) {
    const int row0 = m0 + wm + i * 16 + ((lane >> 4) << 2);
#pragma unroll
    for (int j = 0; j < 4; ++j) {
      const int col = n0 + wn + j * 16 + rsel;
      const float bb = bias[col];
#pragma unroll
      for (int r = 0; r < 4; ++r) {
        const float val = acc[i][j][r] + bb;
        if (OUTF32)
          ((float*)Cout)[(size_t)(row0 + r) * N + col] = val;
        else
          ((unsigned short*)Cout)[(size_t)(row0 + r) * N + col] = f2bf(val);
      }
    }
  }
}

// fused QKV-projection + E-projection GEMM (832 blocks: 768 QKV + 64 E)
__global__ __launch_bounds__(256) void gemm_qkv_e_kernel(
    const unsigned short* __restrict__ xb, const unsigned short* __restrict__ Wqkvb,
    const float* __restrict__ bqkv, unsigned short* __restrict__ QKVb,
    const unsigned short* __restrict__ peb, const unsigned short* __restrict__ Wpb,
    const float* __restrict__ bp, unsigned short* __restrict__ Eb) {
  __shared__ unsigned short sA[128 * 64];
  __shared__ unsigned short sB[128 * 64];
  const int cpx = 104;  // 832/8
  const int bid = (blockIdx.x & 7) * cpx + (blockIdx.x >> 3);
  if (bid < 768) {
    const int mt = bid / 24, nt = bid - mt * 24;
    gemm_tile<0>(xb, Wqkvb, bqkv, QKVb, 3072, 1024, mt << 7, nt << 7,
                 threadIdx.x, sA, sB);
  } else {
    const int b2 = bid - 768;
    gemm_tile<0>(peb, Wpb, bp, Eb, 1024, 1024, (b2 >> 3) << 7, (b2 & 7) << 7,
                 threadIdx.x, sA, sB);
  }
}

// output projection (256 blocks)
__global__ __launch_bounds__(256) void gemm_out_kernel(
    const unsigned short* __restrict__ Ob, const unsigned short* __restrict__ Wob,
    const float* __restrict__ bo, float* __restrict__ out) {
  __shared__ unsigned short sA[128 * 64];
  __shared__ unsigned short sB[128 * 64];
  const int cpx = 32;  // 256/8
  const int bid = (blockIdx.x & 7) * cpx + (blockIdx.x >> 3);
  gemm_tile<1>(Ob, Wob, bo, out, 1024, 1024, (bid >> 3) << 7, (bid & 7) << 7,
               threadIdx.x, sA, sB);
}

// ---------------- fused rel-pos flash attention ----------------
// 512 blocks (XCD-swizzled) x 4 waves; 32 q-rows/wave (two 16-row i-frags);
// KVBLK=64; ONE barrier/kt. K dbuf, E ring-4, Vt dbuf, V regs two tiles
// ahead. Shared K/E/V LDS reads across both i-frags. MFMA section is
// PHASE-SPLIT (SK fully, fence, G fully) to bound register lifetimes —
// round 9's interleaved kb-loop kept kb8+eb8+aU+aV all live and spilled
// (WRITE_SIZE 8.4->16.9MB). sched_barrier(0) stops the scheduler from
// hoisting G-phase LDS reads back into the SK phase.
// LDS = 80KB -> 2 blocks/CU. launch_bounds(256,2).
__global__ __launch_bounds__(256, 2) void attn_kernel(
    const unsigned short* __restrict__ QKV,  // (4096, 3072): Q|K|V
    const unsigned short* __restrict__ E,    // (1024, 1024)
    const float* __restrict__ uvec, const float* __restrict__ vvec,
    unsigned short* __restrict__ O) {        // (4096, 1024)
  __shared__ unsigned short sK[2 * 4096];
  __shared__ unsigned short sE[4 * 4096];
  __shared__ unsigned short sVt[2 * 4096];
  __shared__ unsigned short sP[4][2048];

  const int tid = threadIdx.x;
  const int lane = tid & 63;
  const int wave = tid >> 6;   // 0..3
  const int cpx = gridDim.x >> 3;
  const int bid = (blockIdx.x & 7) * cpx + (blockIdx.x >> 3);
  const int qt = bid & 3;
  const int h = (bid >> 2) & 15;
  const int b = bid >> 6;
  const int q0 = qt << 7;

  const int rsel = lane & 15;
  const int g = lane >> 4;
  const int ilocb = g << 2;
  const int cb0 = 96 - 32 * wave;  // union E-band start (96 cols, 6 frags)

  const unsigned short* Qb = QKV + (size_t)b * 512 * 3072 + h * 64;
  const unsigned short* Kb = Qb + 1024;
  const unsigned short* Vb = Qb + 2048;

  const float sc = 0.125f * 1.44269504088896f;  // 1/sqrt(dh) * log2(e)

  // ---- V(0) regs first ----
  short8 v8b[2];
#pragma unroll
  for (int it = 0; it < 2; ++it) {
    const int c = it * 256 + tid;
    v8b[it] = *(const short8*)(Vb + (size_t)(c >> 3) * 3072 + ((c & 7) << 3));
  }
  // K(0) via global_load_lds
#pragma unroll
  for (int it = 0; it < 2; ++it) {
    const unsigned o = (unsigned)(it * 4096 + wave * 1024 + lane * 16);
    const unsigned row = o >> 7;
    const unsigned x = (o & 127u) ^ ((row & 7u) << 4);
    async_copy16(Kb + (size_t)row * 3072 + (x >> 1),
                 (char*)sK + it * 4096 + wave * 1024);
  }
  // E window halves H = 6-2qt .. 8-2qt into ring slots H&3
#pragma unroll
  for (int hh = 0; hh < 3; ++hh) {
    const int H = 6 - 2 * qt + hh;
#pragma unroll
    for (int it = 0; it < 2; ++it) {
      const unsigned o = (unsigned)(it * 4096 + wave * 1024 + lane * 16);
      const unsigned row = o >> 7;
      const unsigned x = (o & 127u) ^ ((row & 7u) << 4);
      async_copy16(E + (size_t)(H * 64 + (int)row) * 1024 + h * 64 + (x >> 1),
                   (char*)sE + (H & 3) * 8192 + it * 4096 + wave * 1024);
    }
  }

  // ---- Q fragments (A-layout) for both i-frags, pre-scaled ----
  short8 aU[2][2], aV[2][2];
#pragma unroll
  for (int f = 0; f < 2; ++f) {
    const int qrow = q0 + 32 * wave + 16 * f + rsel;
    const int dob = g * 8;
#pragma unroll
    for (int kb = 0; kb < 2; ++kb) {
      short8 q8 = *(const short8*)(Qb + (size_t)qrow * 3072 + kb * 32 + dob);
#pragma unroll
      for (int j = 0; j < 8; ++j) {
        const float qf = bf2f((unsigned short)q8[j]);
        aU[f][kb][j] = (short)f2bf((qf + uvec[h * 64 + kb * 32 + dob + j]) * sc);
        aV[f][kb][j] = (short)f2bf((qf + vvec[h * 64 + kb * 32 + dob + j]) * sc);
      }
    }
  }

  // transpose V(0) -> Vt[0] (DPP lane^8 exchange, b32 writes)
#pragma unroll
  for (int it = 0; it < 2; ++it) {
    const int c = it * 256 + tid;
    const int trow = c >> 3;
    const int db = (c & 7) << 3;
    const int odd = trow & 1;
    const int kp = (trow & ~1) * 2;
    const uint4v dw = __builtin_bit_cast(uint4v, v8b[it]);
#pragma unroll
    for (int p = 0; p < 4; ++p) {
      const unsigned mine = dw[p];
      const unsigned other = dpp_xor8(mine);
      const unsigned res = odd ? ((mine & 0xffff0000u) | (other >> 16))
                               : ((other << 16) | (mine & 0xffffu));
      const int d = db + 2 * p + odd;
      *(unsigned*)((char*)sVt + d * 128 + (kp ^ (((d ^ (d >> 3)) & 7) << 4))) = res;
    }
  }
  // V(1) -> regs
#pragma unroll
  for (int it = 0; it < 2; ++it) {
    const int c = it * 256 + tid;
    v8b[it] = *(const short8*)(Vb + (size_t)(64 + (c >> 3)) * 3072 + ((c & 7) << 3));
  }

  // skew-gather shuffle constants (kt- and f-invariant)
  int srcLn[4];
  bool hiSel[4];
#pragma unroll
  for (int r = 0; r < 4; ++r) {
    const int offs = 15 - (ilocb + r) + rsel;  // 0..30
    srcLn[r] = (lane & 48) | (offs & 15);
    hiSel[r] = offs >= 16;
  }

  float mrun[2][4], lrun[2][4];
  f32x4 oacc[2][4];
#pragma unroll
  for (int f = 0; f < 2; ++f)
#pragma unroll
    for (int r = 0; r < 4; ++r) { mrun[f][r] = -INFINITY; lrun[f][r] = 0.f; }
#pragma unroll
  for (int f = 0; f < 2; ++f)
#pragma unroll
    for (int n = 0; n < 4; ++n) oacc[f][n] = f32x4{0.f, 0.f, 0.f, 0.f};

  for (int kt = 0; kt < 8; ++kt) {
    const int k0 = kt << 6;
    const int cur = kt & 1;
    const int H0 = 6 - 2 * qt + kt;  // window low half index

    __syncthreads();  // single barrier: drains prefetched glds

    if (kt < 7) {
      const int kn = k0 + 64;
      // K(kt+1) -> sK[cur^1]
#pragma unroll
      for (int it = 0; it < 2; ++it) {
        const unsigned o = (unsigned)(it * 4096 + wave * 1024 + lane * 16);
        const unsigned row = o >> 7;
        const unsigned x = (o & 127u) ^ ((row & 7u) << 4);
        async_copy16(Kb + (size_t)(kn + (int)row) * 3072 + (x >> 1),
                     (char*)sK + (cur ^ 1) * 8192 + it * 4096 + wave * 1024);
      }
      // E half H0+3 -> ring slot (H0+3)&3
      {
        const int H = H0 + 3;
#pragma unroll
        for (int it = 0; it < 2; ++it) {
          const unsigned o = (unsigned)(it * 4096 + wave * 1024 + lane * 16);
          const unsigned row = o >> 7;
          const unsigned x = (o & 127u) ^ ((row & 7u) << 4);
          async_copy16(E + (size_t)(H * 64 + (int)row) * 1024 + h * 64 + (x >> 1),
                       (char*)sE + (H & 3) * 8192 + it * 4096 + wave * 1024);
        }
      }
      // transpose V(kt+1) (in v8b) -> Vt[cur^1]
#pragma unroll
      for (int it = 0; it < 2; ++it) {
        const int c = it * 256 + tid;
        const int trow = c >> 3;
        const int db = (c & 7) << 3;
        const int odd = trow & 1;
        const int kp = (trow & ~1) * 2;
        const uint4v dw = __builtin_bit_cast(uint4v, v8b[it]);
#pragma unroll
        for (int p = 0; p < 4; ++p) {
          const unsigned mine = dw[p];
          const unsigned other = dpp_xor8(mine);
          const unsigned res = odd ? ((mine & 0xffff0000u) | (other >> 16))
                                   : ((other << 16) | (mine & 0xffffu));
          const int d = db + 2 * p + odd;
          *(unsigned*)((char*)sVt + (cur ^ 1) * 8192 + d * 128 +
                       (kp ^ (((d ^ (d >> 3)) & 7) << 4))) = res;
        }
      }
      // V(kt+2) -> regs
      if (kt < 6) {
#pragma unroll
        for (int it = 0; it < 2; ++it) {
          const int c = it * 256 + tid;
          v8b[it] = *(const short8*)(Vb + (size_t)(kn + 64 + (c >> 3)) * 3072 +
                                     ((c & 7) << 3));
        }
      }
    }

    f32x4 skacc[2][4], gacc[2][5];
#pragma unroll
    for (int f = 0; f < 2; ++f) {
#pragma unroll
      for (int nf = 0; nf < 4; ++nf) skacc[f][nf] = f32x4{0.f, 0.f, 0.f, 0.f};
#pragma unroll
      for (int cf = 0; cf < 5; ++cf) gacc[f][cf] = f32x4{0.f, 0.f, 0.f, 0.f};
    }

    // ---- Phase 1: SK = Qu@K^T (kb8 + aU live only here) ----
    __builtin_amdgcn_s_setprio(1);
#pragma unroll
    for (int kb = 0; kb < 2; ++kb) {
      const int kbyte = kb * 64 + g * 16;
      short8 kb8[4];
#pragma unroll
      for (int nf = 0; nf < 4; ++nf) {
        const int rb = nf * 16 + rsel;
        kb8[nf] = *(const short8*)((const char*)sK + cur * 8192 + rb * 128 +
                                   (kbyte ^ ((rb & 7) << 4)));
      }
#pragma unroll
      for (int f = 0; f < 2; ++f)
#pragma unroll
        for (int nf = 0; nf < 4; ++nf)
          skacc[f][nf] = __builtin_amdgcn_mfma_f32_16x16x32_bf16(
              aU[f][kb], kb8[nf], skacc[f][nf], 0, 0, 0);
    }
    __builtin_amdgcn_sched_barrier(0);  // keep eb8 reads out of phase 1

    // ---- Phase 2: G = Qv@Ewin^T (eb8 + aV live only here) ----
#pragma unroll
    for (int kb = 0; kb < 2; ++kb) {
      const int kbyte = kb * 64 + g * 16;
      short8 eb8[6];
#pragma unroll
      for (int cfu = 0; cfu < 6; ++cfu) {
        const int rowbase = cb0 + 16 * cfu;
        const int rb = rowbase + rsel;
        const int slot = (H0 + (rowbase >> 6)) & 3;
        eb8[cfu] = *(const short8*)((const char*)sE + slot * 8192 +
                                    (rb & 63) * 128 + (kbyte ^ ((rb & 7) << 4)));
      }
#pragma unroll
      for (int f = 0; f < 2; ++f)
#pragma unroll
        for (int j = 0; j < 5; ++j)
          gacc[f][j] = __builtin_amdgcn_mfma_f32_16x16x32_bf16(
              aV[f][kb], eb8[j + 1 - f], gacc[f][j], 0, 0, 0);
    }
    __builtin_amdgcn_s_setprio(0);

    // diag-gather G via bpermute: S[f][i,j] += G[f][i, 15-i+j(+band)]
#pragma unroll
    for (int f = 0; f < 2; ++f)
#pragma unroll
      for (int r = 0; r < 4; ++r) {
        float gsh[5];
#pragma unroll
        for (int cf = 0; cf < 5; ++cf)
          gsh[cf] = __shfl(gacc[f][cf][r], srcLn[r], 64);
#pragma unroll
        for (int nf = 0; nf < 4; ++nf)
          skacc[f][nf][r] += hiSel[r] ? gsh[nf + 1] : gsh[nf];
      }

    // online softmax in exp2 domain; reductions via DPP (VALU)
    float scl[2][4];
#pragma unroll
    for (int f = 0; f < 2; ++f) {
      float rsum[4];
#pragma unroll
      for (int r = 0; r < 4; ++r) {
        float t = fmaxf(fmaxf(skacc[f][0][r], skacc[f][1][r]),
                        fmaxf(skacc[f][2][r], skacc[f][3][r]));
        t = rowmax16(t);
        const float mnew = fmaxf(mrun[f][r], t);
        scl[f][r] = __builtin_amdgcn_exp2f(mrun[f][r] - mnew);
        mrun[f][r] = mnew;
        rsum[r] = 0.f;
      }
#pragma unroll
      for (int nf = 0; nf < 4; ++nf)
#pragma unroll
        for (int r = 0; r < 4; ++r) {
          const float p = __builtin_amdgcn_exp2f(skacc[f][nf][r] - mrun[f][r]);
          rsum[r] += p;
          const int rloc = 16 * f + ilocb + r;
          const int jb = (nf * 16 + rsel) * 2;
          *(unsigned short*)((char*)sP[wave] + rloc * 128 +
                             (jb ^ ((rloc & 7) << 4))) = f2bf(p);
        }
#pragma unroll
      for (int r = 0; r < 4; ++r)
        lrun[f][r] = lrun[f][r] * scl[f][r] + rowsum16(rsum[r]);
#pragma unroll
      for (int nf = 0; nf < 4; ++nf)
#pragma unroll
        for (int r = 0; r < 4; ++r) oacc[f][nf][r] *= scl[f][r];
    }

    // O += P@V : A-frags per i-frag from sP, B-frags shared from sVt[cur]
    __builtin_amdgcn_s_setprio(1);
#pragma unroll
    for (int kb = 0; kb < 2; ++kb) {
      const int kbyte = kb * 64 + g * 16;
      short8 ap[2];
#pragma unroll
      for (int f = 0; f < 2; ++f) {
        const int pr = 16 * f + rsel;
        ap[f] = *(const short8*)((const char*)sP[wave] + pr * 128 +
                                 (kbyte ^ ((pr & 7) << 4)));
      }
#pragma unroll
      for (int nf = 0; nf < 4; ++nf) {
        const int rv = nf * 16 + rsel;
        short8 vb8 = *(const short8*)((const char*)sVt + cur * 8192 + rv * 128 +
                                      (kbyte ^ (((rv ^ (rv >> 3)) & 7) << 4)));
#pragma unroll
        for (int f = 0; f < 2; ++f)
          oacc[f][nf] = __builtin_amdgcn_mfma_f32_16x16x32_bf16(
              ap[f], vb8, oacc[f][nf], 0, 0, 0);
      }
    }
    __builtin_amdgcn_s_setprio(0);
  }

  // epilogue
#pragma unroll
  for (int f = 0; f < 2; ++f)
#pragma unroll
    for (int nf = 0; nf < 4; ++nf)
#pragma unroll
      for (int r = 0; r < 4; ++r) {
        const int t = q0 + 32 * wave + 16 * f + ilocb + r;
        const int col = h * 64 + nf * 16 + rsel;
        O[(size_t)(b * 512 + t) * 1024 + col] = f2bf(oacc[f][nf][r] / lrun[f][r]);
      }
}

// ---------------- launch ----------------
extern "C" void kernel_launch(void* const* d_in, const int* in_sizes, int n_in,
                              void* d_out, int out_size, void* d_ws, size_t ws_size,
                              hipStream_t stream) {
  const float* x  = (const float*)d_in[0];
  const float* Wq = (const float*)d_in[1];
  const float* bq = (const float*)d_in[2];
  const float* Wk = (const float*)d_in[3];
  const float* bk = (const float*)d_in[4];
  const float* Wv = (const float*)d_in[5];
  const float* bv = (const float*)d_in[6];
  const float* Wp = (const float*)d_in[7];
  const float* bp = (const float*)d_in[8];
  const float* Wo = (const float*)d_in[9];
  const float* bo = (const float*)d_in[10];
  const float* u  = (const float*)d_in[11];
  const float* v  = (const float*)d_in[12];
  float* out = (float*)d_out;

  char* ws = (char*)d_ws;
  const size_t MB = 1024 * 1024;
  unsigned short* xb    = (unsigned short*)(ws);             // 4096x1024 bf16
  unsigned short* Wqkvb = (unsigned short*)(ws + 8 * MB);    // 3072x1024
  unsigned short* Wpb   = (unsigned short*)(ws + 14 * MB);   // 1024x1024
  unsigned short* Wob   = (unsigned short*)(ws + 16 * MB);   // 1024x1024
  unsigned short* peb   = (unsigned short*)(ws + 18 * MB);   // 1024x1024
  unsigned short* QKVb  = (unsigned short*)(ws + 20 * MB);   // 4096x3072
  unsigned short* Eb    = (unsigned short*)(ws + 44 * MB);   // 1024x1024
  unsigned short* Ob    = (unsigned short*)(ws + 46 * MB);   // 4096x1024
  float* bqkv           = (float*)(ws + 54 * MB);            // 3072 f32

  prep_kernel<<<dim3(11276), dim3(256), 0, stream>>>(
      x, Wq, Wk, Wv, Wp, Wo, bq, bk, bv, xb, Wqkvb, Wpb, Wob, peb, bqkv);

  gemm_qkv_e_kernel<<<dim3(832), dim3(256), 0, stream>>>(
      xb, Wqkvb, bqkv, QKVb, peb, Wpb, bp, Eb);
  attn_kernel<<<dim3(512), dim3(256), 0, stream>>>(QKVb, Eb, u, v, Ob);
  gemm_out_kernel<<<dim3(256), dim3(256), 0, stream>>>(Ob, Wob, bo, out);
}

// Round 11
// 113.137 us; speedup vs baseline: 1.0693x; 1.0529x over previous
//
#include <hip/hip_runtime.h>
#include <hip/hip_bf16.h>
#include <cmath>

using short8  = __attribute__((ext_vector_type(8))) short;
using f32x4   = __attribute__((ext_vector_type(4))) float;
using uint4v  = __attribute__((ext_vector_type(4))) unsigned;

#define DEV static __device__ __forceinline__

DEV unsigned short f2bf(float f) {
  union { float f; unsigned u; } v; v.f = f;
  unsigned r = v.u + 0x7FFFu + ((v.u >> 16) & 1u);
  return (unsigned short)(r >> 16);
}
DEV float bf2f(unsigned short b) {
  union { unsigned u; float f; } v; v.u = ((unsigned)b) << 16;
  return v.f;
}

DEV void async_copy16(const void* g, void* l) {
  __builtin_amdgcn_global_load_lds(
      (const __attribute__((address_space(1))) void*)g,
      (__attribute__((address_space(3))) void*)l, 16, 0, 0);
}

// DPP helpers: row_ror:N within 16-lane rows (VALU pipe, no LDS)
#define DPPF(x, ctrl)                                                     \
  __builtin_bit_cast(float, __builtin_amdgcn_update_dpp(                  \
      __builtin_bit_cast(int, (x)), __builtin_bit_cast(int, (x)), (ctrl), \
      0xF, 0xF, false))

DEV float rowmax16(float t) {
  t = fmaxf(t, DPPF(t, 0x128));
  t = fmaxf(t, DPPF(t, 0x124));
  t = fmaxf(t, DPPF(t, 0x122));
  t = fmaxf(t, DPPF(t, 0x121));
  return t;
}
DEV float rowsum16(float t) {
  t += DPPF(t, 0x128);
  t += DPPF(t, 0x124);
  t += DPPF(t, 0x122);
  t += DPPF(t, 0x121);
  return t;
}
DEV unsigned dpp_xor8(unsigned x) {  // lane^8 within each 16-lane row
  return (unsigned)__builtin_amdgcn_update_dpp((int)x, (int)x, 0x128, 0xF, 0xF, false);
}

// ---------------- fused prep: f32->bf16 converts + PE table + bias pack ----
__global__ __launch_bounds__(256) void prep_kernel(
    const float* __restrict__ x,  const float* __restrict__ Wq,
    const float* __restrict__ Wk, const float* __restrict__ Wv,
    const float* __restrict__ Wp, const float* __restrict__ Wo,
    const float* __restrict__ bq, const float* __restrict__ bk,
    const float* __restrict__ bv,
    unsigned short* __restrict__ xb, unsigned short* __restrict__ Wqkvb,
    unsigned short* __restrict__ Wpb, unsigned short* __restrict__ Wob,
    unsigned short* __restrict__ peb, float* __restrict__ bqkv) {
  const int blk = blockIdx.x;
  const int tid = threadIdx.x;
  if (blk < 9216) {  // converts
    const float* src;
    unsigned short* dst;
    int i;
    if (blk < 4096) {
      src = x; dst = xb; i = blk * 256 + tid;
    } else {
      const int w = (blk - 4096) >> 10;
      i = ((blk - 4096) & 1023) * 256 + tid;
      if      (w == 0) { src = Wq; dst = Wqkvb; }
      else if (w == 1) { src = Wk; dst = Wqkvb + 1048576; }
      else if (w == 2) { src = Wv; dst = Wqkvb + 2097152; }
      else if (w == 3) { src = Wp; dst = Wpb; }
      else             { src = Wo; dst = Wob; }
    }
    float4 v = ((const float4*)src)[i];
    ushort4 o;
    o.x = f2bf(v.x); o.y = f2bf(v.y); o.z = f2bf(v.z); o.w = f2bf(v.w);
    ((ushort4*)dst)[i] = o;
  } else if (blk < 11264) {  // PE table
    const int idx = (blk - 9216) * 256 + tid;
    const int r = idx >> 9;
    const int m = idx & 511;
    const float inv_freq = __expf((float)m * -0.017988946039016004f);
    const float ang = (float)(511 - r) * inv_freq;
    peb[(size_t)r * 1024 + 2 * m]     = f2bf(sinf(ang));
    peb[(size_t)r * 1024 + 2 * m + 1] = f2bf(cosf(ang));
  } else {  // bias pack
    const int i = (blk - 11264) * 256 + tid;
    const float* s = (i < 1024) ? bq : (i < 2048) ? bk : bv;
    bqkv[i] = s[i & 1023];
  }
}

// ---------------- GEMM tile body: C[M,N] = A[M,K] @ B[N,K]^T + bias[N] -----
template <int OUTF32>
DEV void gemm_tile(const unsigned short* __restrict__ A,
                   const unsigned short* __restrict__ B,
                   const float* __restrict__ bias, void* __restrict__ Cout,
                   int N, int K, int m0, int n0, int tid,
                   unsigned short* sA, unsigned short* sB) {
  const int lane = tid & 63;
  const int wave = tid >> 6;

  const unsigned short* gA[4];
  const unsigned short* gB[4];
  unsigned ldst[4];
#pragma unroll
  for (int it = 0; it < 4; ++it) {
    unsigned o = (unsigned)(it * 4096 + wave * 1024 + lane * 16);
    unsigned row = o >> 7;
    unsigned x = (o & 127u) ^ ((row & 7u) << 4);
    ldst[it] = it * 4096 + wave * 1024;
    gA[it] = A + (size_t)(m0 + (int)row) * K + (x >> 1);
    gB[it] = B + (size_t)(n0 + (int)row) * K + (x >> 1);
  }

  f32x4 acc[4][4];
#pragma unroll
  for (int i = 0; i < 4; ++i)
#pragma unroll
    for (int j = 0; j < 4; ++j) acc[i][j] = f32x4{0.f, 0.f, 0.f, 0.f};

  const int wm = (wave >> 1) << 6;
  const int wn = (wave & 1) << 6;
  const int rsel = lane & 15;
  const int ksel = (lane >> 4) << 4;

  for (int k0 = 0; k0 < K; k0 += 64) {
#pragma unroll
    for (int it = 0; it < 4; ++it) {
      async_copy16(gA[it] + k0, (char*)sA + ldst[it]);
      async_copy16(gB[it] + k0, (char*)sB + ldst[it]);
    }
    __syncthreads();
#pragma unroll
    for (int kb = 0; kb < 2; ++kb) {
      const int kbyte = kb * 64 + ksel;
      short8 af[4], bf8[4];
#pragma unroll
      for (int i = 0; i < 4; ++i) {
        const int ra = wm + i * 16 + rsel;
        af[i] = *(const short8*)((const char*)sA + ra * 128 + (kbyte ^ ((ra & 7) << 4)));
        const int rb = wn + i * 16 + rsel;
        bf8[i] = *(const short8*)((const char*)sB + rb * 128 + (kbyte ^ ((rb & 7) << 4)));
      }
#pragma unroll
      for (int i = 0; i < 4; ++i)
#pragma unroll
        for (int j = 0; j < 4; ++j)
          acc[i][j] = __builtin_amdgcn_mfma_f32_16x16x32_bf16(af[i], bf8[j], acc[i][j], 0, 0, 0);
    }
    __syncthreads();
  }

#pragma unroll
  for (int i = 0; i < 4; ++i) {
    const int row0 = m0 + wm + i * 16 + ((lane >> 4) << 2);
#pragma unroll
    for (int j = 0; j < 4; ++j) {
      const int col = n0 + wn + j * 16 + rsel;
      const float bb = bias[col];
#pragma unroll
      for (int r = 0; r < 4; ++r) {
        const float val = acc[i][j][r] + bb;
        if (OUTF32)
          ((float*)Cout)[(size_t)(row0 + r) * N + col] = val;
        else
          ((unsigned short*)Cout)[(size_t)(row0 + r) * N + col] = f2bf(val);
      }
    }
  }
}

// fused QKV-projection + E-projection GEMM (832 blocks: 768 QKV + 64 E)
__global__ __launch_bounds__(256) void gemm_qkv_e_kernel(
    const unsigned short* __restrict__ xb, const unsigned short* __restrict__ Wqkvb,
    const float* __restrict__ bqkv, unsigned short* __restrict__ QKVb,
    const unsigned short* __restrict__ peb, const unsigned short* __restrict__ Wpb,
    const float* __restrict__ bp, unsigned short* __restrict__ Eb) {
  __shared__ unsigned short sA[128 * 64];
  __shared__ unsigned short sB[128 * 64];
  const int cpx = 104;  // 832/8
  const int bid = (blockIdx.x & 7) * cpx + (blockIdx.x >> 3);
  if (bid < 768) {
    const int mt = bid / 24, nt = bid - mt * 24;
    gemm_tile<0>(xb, Wqkvb, bqkv, QKVb, 3072, 1024, mt << 7, nt << 7,
                 threadIdx.x, sA, sB);
  } else {
    const int b2 = bid - 768;
    gemm_tile<0>(peb, Wpb, bp, Eb, 1024, 1024, (b2 >> 3) << 7, (b2 & 7) << 7,
                 threadIdx.x, sA, sB);
  }
}

// output projection (256 blocks)
__global__ __launch_bounds__(256) void gemm_out_kernel(
    const unsigned short* __restrict__ Ob, const unsigned short* __restrict__ Wob,
    const float* __restrict__ bo, float* __restrict__ out) {
  __shared__ unsigned short sA[128 * 64];
  __shared__ unsigned short sB[128 * 64];
  const int cpx = 32;  // 256/8
  const int bid = (blockIdx.x & 7) * cpx + (blockIdx.x >> 3);
  gemm_tile<1>(Ob, Wob, bo, out, 1024, 1024, (bid >> 3) << 7, (bid & 7) << 7,
               threadIdx.x, sA, sB);
}

// ---------------- fused rel-pos flash attention ----------------
// 512 blocks (XCD-swizzled) x 4 waves; 32 q-rows/wave (two 16-row i-frags);
// KVBLK=64; ONE barrier/kt. K dbuf, E ring-4, Vt dbuf, V regs two tiles
// ahead. Shared K/E/V LDS reads across both i-frags.
// VGPR budget at (256,2) is 256 unified; compiler splits ~128 arch VGPR +
// 128 AGPR. Rounds 9/10 spilled because kb8[4](16)+eb8[6](24) batch loads
// pushed the VGPR half to ~145. Fix: stream operand frags in groups of
// 2 (K) / 3 (E) on named registers -> peak ~117, no spill.
// LDS = 80KB -> 2 blocks/CU.
__global__ __launch_bounds__(256, 2) void attn_kernel(
    const unsigned short* __restrict__ QKV,  // (4096, 3072): Q|K|V
    const unsigned short* __restrict__ E,    // (1024, 1024)
    const float* __restrict__ uvec, const float* __restrict__ vvec,
    unsigned short* __restrict__ O) {        // (4096, 1024)
  __shared__ unsigned short sK[2 * 4096];
  __shared__ unsigned short sE[4 * 4096];
  __shared__ unsigned short sVt[2 * 4096];
  __shared__ unsigned short sP[4][2048];

  const int tid = threadIdx.x;
  const int lane = tid & 63;
  const int wave = tid >> 6;   // 0..3
  const int cpx = gridDim.x >> 3;
  const int bid = (blockIdx.x & 7) * cpx + (blockIdx.x >> 3);
  const int qt = bid & 3;
  const int h = (bid >> 2) & 15;
  const int b = bid >> 6;
  const int q0 = qt << 7;

  const int rsel = lane & 15;
  const int g = lane >> 4;
  const int ilocb = g << 2;
  const int cb0 = 96 - 32 * wave;  // union E-band start (96 cols, 6 frags)

  const unsigned short* Qb = QKV + (size_t)b * 512 * 3072 + h * 64;
  const unsigned short* Kb = Qb + 1024;
  const unsigned short* Vb = Qb + 2048;

  const float sc = 0.125f * 1.44269504088896f;  // 1/sqrt(dh) * log2(e)

  // ---- V(0) regs first ----
  short8 v8b[2];
#pragma unroll
  for (int it = 0; it < 2; ++it) {
    const int c = it * 256 + tid;
    v8b[it] = *(const short8*)(Vb + (size_t)(c >> 3) * 3072 + ((c & 7) << 3));
  }
  // K(0) via global_load_lds
#pragma unroll
  for (int it = 0; it < 2; ++it) {
    const unsigned o = (unsigned)(it * 4096 + wave * 1024 + lane * 16);
    const unsigned row = o >> 7;
    const unsigned x = (o & 127u) ^ ((row & 7u) << 4);
    async_copy16(Kb + (size_t)row * 3072 + (x >> 1),
                 (char*)sK + it * 4096 + wave * 1024);
  }
  // E window halves H = 6-2qt .. 8-2qt into ring slots H&3
#pragma unroll
  for (int hh = 0; hh < 3; ++hh) {
    const int H = 6 - 2 * qt + hh;
#pragma unroll
    for (int it = 0; it < 2; ++it) {
      const unsigned o = (unsigned)(it * 4096 + wave * 1024 + lane * 16);
      const unsigned row = o >> 7;
      const unsigned x = (o & 127u) ^ ((row & 7u) << 4);
      async_copy16(E + (size_t)(H * 64 + (int)row) * 1024 + h * 64 + (x >> 1),
                   (char*)sE + (H & 3) * 8192 + it * 4096 + wave * 1024);
    }
  }

  // ---- Q fragments (A-layout) for both i-frags, pre-scaled ----
  short8 aU[2][2], aV[2][2];
#pragma unroll
  for (int f = 0; f < 2; ++f) {
    const int qrow = q0 + 32 * wave + 16 * f + rsel;
    const int dob = g * 8;
#pragma unroll
    for (int kb = 0; kb < 2; ++kb) {
      short8 q8 = *(const short8*)(Qb + (size_t)qrow * 3072 + kb * 32 + dob);
#pragma unroll
      for (int j = 0; j < 8; ++j) {
        const float qf = bf2f((unsigned short)q8[j]);
        aU[f][kb][j] = (short)f2bf((qf + uvec[h * 64 + kb * 32 + dob + j]) * sc);
        aV[f][kb][j] = (short)f2bf((qf + vvec[h * 64 + kb * 32 + dob + j]) * sc);
      }
    }
  }

  // transpose V(0) -> Vt[0] (DPP lane^8 exchange, b32 writes)
#pragma unroll
  for (int it = 0; it < 2; ++it) {
    const int c = it * 256 + tid;
    const int trow = c >> 3;
    const int db = (c & 7) << 3;
    const int odd = trow & 1;
    const int kp = (trow & ~1) * 2;
    const uint4v dw = __builtin_bit_cast(uint4v, v8b[it]);
#pragma unroll
    for (int p = 0; p < 4; ++p) {
      const unsigned mine = dw[p];
      const unsigned other = dpp_xor8(mine);
      const unsigned res = odd ? ((mine & 0xffff0000u) | (other >> 16))
                               : ((other << 16) | (mine & 0xffffu));
      const int d = db + 2 * p + odd;
      *(unsigned*)((char*)sVt + d * 128 + (kp ^ (((d ^ (d >> 3)) & 7) << 4))) = res;
    }
  }
  // V(1) -> regs
#pragma unroll
  for (int it = 0; it < 2; ++it) {
    const int c = it * 256 + tid;
    v8b[it] = *(const short8*)(Vb + (size_t)(64 + (c >> 3)) * 3072 + ((c & 7) << 3));
  }

  // skew-gather shuffle constants (kt- and f-invariant)
  int srcLn[4];
  bool hiSel[4];
#pragma unroll
  for (int r = 0; r < 4; ++r) {
    const int offs = 15 - (ilocb + r) + rsel;  // 0..30
    srcLn[r] = (lane & 48) | (offs & 15);
    hiSel[r] = offs >= 16;
  }

  float mrun[2][4], lrun[2][4];
  f32x4 oacc[2][4];
#pragma unroll
  for (int f = 0; f < 2; ++f)
#pragma unroll
    for (int r = 0; r < 4; ++r) { mrun[f][r] = -INFINITY; lrun[f][r] = 0.f; }
#pragma unroll
  for (int f = 0; f < 2; ++f)
#pragma unroll
    for (int n = 0; n < 4; ++n) oacc[f][n] = f32x4{0.f, 0.f, 0.f, 0.f};

  for (int kt = 0; kt < 8; ++kt) {
    const int k0 = kt << 6;
    const int cur = kt & 1;
    const int H0 = 6 - 2 * qt + kt;  // window low half index

    __syncthreads();  // single barrier: drains prefetched glds

    if (kt < 7) {
      const int kn = k0 + 64;
      // K(kt+1) -> sK[cur^1]
#pragma unroll
      for (int it = 0; it < 2; ++it) {
        const unsigned o = (unsigned)(it * 4096 + wave * 1024 + lane * 16);
        const unsigned row = o >> 7;
        const unsigned x = (o & 127u) ^ ((row & 7u) << 4);
        async_copy16(Kb + (size_t)(kn + (int)row) * 3072 + (x >> 1),
                     (char*)sK + (cur ^ 1) * 8192 + it * 4096 + wave * 1024);
      }
      // E half H0+3 -> ring slot (H0+3)&3
      {
        const int H = H0 + 3;
#pragma unroll
        for (int it = 0; it < 2; ++it) {
          const unsigned o = (unsigned)(it * 4096 + wave * 1024 + lane * 16);
          const unsigned row = o >> 7;
          const unsigned x = (o & 127u) ^ ((row & 7u) << 4);
          async_copy16(E + (size_t)(H * 64 + (int)row) * 1024 + h * 64 + (x >> 1),
                       (char*)sE + (H & 3) * 8192 + it * 4096 + wave * 1024);
        }
      }
      // transpose V(kt+1) (in v8b, complete since barrier) -> Vt[cur^1]
#pragma unroll
      for (int it = 0; it < 2; ++it) {
        const int c = it * 256 + tid;
        const int trow = c >> 3;
        const int db = (c & 7) << 3;
        const int odd = trow & 1;
        const int kp = (trow & ~1) * 2;
        const uint4v dw = __builtin_bit_cast(uint4v, v8b[it]);
#pragma unroll
        for (int p = 0; p < 4; ++p) {
          const unsigned mine = dw[p];
          const unsigned other = dpp_xor8(mine);
          const unsigned res = odd ? ((mine & 0xffff0000u) | (other >> 16))
                                   : ((other << 16) | (mine & 0xffffu));
          const int d = db + 2 * p + odd;
          *(unsigned*)((char*)sVt + (cur ^ 1) * 8192 + d * 128 +
                       (kp ^ (((d ^ (d >> 3)) & 7) << 4))) = res;
        }
      }
    }

    f32x4 skacc[2][4], gacc[2][5];
#pragma unroll
    for (int f = 0; f < 2; ++f) {
#pragma unroll
      for (int nf = 0; nf < 4; ++nf) skacc[f][nf] = f32x4{0.f, 0.f, 0.f, 0.f};
#pragma unroll
      for (int cf = 0; cf < 5; ++cf) gacc[f][cf] = f32x4{0.f, 0.f, 0.f, 0.f};
    }

    // ---- Phase 1: SK = Qu@K^T ; K frags streamed in pairs (8 VGPR live) --
    __builtin_amdgcn_s_setprio(1);
#pragma unroll
    for (int kb = 0; kb < 2; ++kb) {
      const int kbyte = kb * 64 + g * 16;
      const char* sKc = (const char*)sK + cur * 8192;
      short8 ka, kbb;
      {
        const int r0 = rsel, r1 = 16 + rsel;
        ka  = *(const short8*)(sKc + r0 * 128 + (kbyte ^ ((r0 & 7) << 4)));
        kbb = *(const short8*)(sKc + r1 * 128 + (kbyte ^ ((r1 & 7) << 4)));
      }
      skacc[0][0] = __builtin_amdgcn_mfma_f32_16x16x32_bf16(aU[0][kb], ka,  skacc[0][0], 0, 0, 0);
      skacc[1][0] = __builtin_amdgcn_mfma_f32_16x16x32_bf16(aU[1][kb], ka,  skacc[1][0], 0, 0, 0);
      skacc[0][1] = __builtin_amdgcn_mfma_f32_16x16x32_bf16(aU[0][kb], kbb, skacc[0][1], 0, 0, 0);
      skacc[1][1] = __builtin_amdgcn_mfma_f32_16x16x32_bf16(aU[1][kb], kbb, skacc[1][1], 0, 0, 0);
      {
        const int r0 = 32 + rsel, r1 = 48 + rsel;
        ka  = *(const short8*)(sKc + r0 * 128 + (kbyte ^ ((r0 & 7) << 4)));
        kbb = *(const short8*)(sKc + r1 * 128 + (kbyte ^ ((r1 & 7) << 4)));
      }
      skacc[0][2] = __builtin_amdgcn_mfma_f32_16x16x32_bf16(aU[0][kb], ka,  skacc[0][2], 0, 0, 0);
      skacc[1][2] = __builtin_amdgcn_mfma_f32_16x16x32_bf16(aU[1][kb], ka,  skacc[1][2], 0, 0, 0);
      skacc[0][3] = __builtin_amdgcn_mfma_f32_16x16x32_bf16(aU[0][kb], kbb, skacc[0][3], 0, 0, 0);
      skacc[1][3] = __builtin_amdgcn_mfma_f32_16x16x32_bf16(aU[1][kb], kbb, skacc[1][3], 0, 0, 0);
    }
    __builtin_amdgcn_sched_barrier(0);  // keep E reads out of phase 1

    // V(kt+2) -> regs (issued here: hides under phase 2, shortens live range)
    if (kt < 6) {
#pragma unroll
      for (int it = 0; it < 2; ++it) {
        const int c = it * 256 + tid;
        v8b[it] = *(const short8*)(Vb + (size_t)(k0 + 128 + (c >> 3)) * 3072 +
                                   ((c & 7) << 3));
      }
    }

    // ---- Phase 2: G = Qv@Ewin^T ; E frags streamed in triples (12 VGPR) --
    // gacc[f][j] consumes e[j+1-f]
#pragma unroll
    for (int kb = 0; kb < 2; ++kb) {
      const int kbyte = kb * 64 + g * 16;
      short8 e0, e1, e2;
#define LDE(cfu)                                                              \
  ({                                                                          \
    const int rowbase = cb0 + 16 * (cfu);                                     \
    const int rb = rowbase + rsel;                                            \
    const int slot = (H0 + (rowbase >> 6)) & 3;                               \
    *(const short8*)((const char*)sE + slot * 8192 + (rb & 63) * 128 +        \
                     (kbyte ^ ((rb & 7) << 4)));                              \
  })
      e0 = LDE(0); e1 = LDE(1); e2 = LDE(2);
      gacc[1][0] = __builtin_amdgcn_mfma_f32_16x16x32_bf16(aV[1][kb], e0, gacc[1][0], 0, 0, 0);
      gacc[0][0] = __builtin_amdgcn_mfma_f32_16x16x32_bf16(aV[0][kb], e1, gacc[0][0], 0, 0, 0);
      gacc[1][1] = __builtin_amdgcn_mfma_f32_16x16x32_bf16(aV[1][kb], e1, gacc[1][1], 0, 0, 0);
      gacc[0][1] = __builtin_amdgcn_mfma_f32_16x16x32_bf16(aV[0][kb], e2, gacc[0][1], 0, 0, 0);
      gacc[1][2] = __builtin_amdgcn_mfma_f32_16x16x32_bf16(aV[1][kb], e2, gacc[1][2], 0, 0, 0);
      e0 = LDE(3); e1 = LDE(4); e2 = LDE(5);
      gacc[0][2] = __builtin_amdgcn_mfma_f32_16x16x32_bf16(aV[0][kb], e0, gacc[0][2], 0, 0, 0);
      gacc[1][3] = __builtin_amdgcn_mfma_f32_16x16x32_bf16(aV[1][kb], e0, gacc[1][3], 0, 0, 0);
      gacc[0][3] = __builtin_amdgcn_mfma_f32_16x16x32_bf16(aV[0][kb], e1, gacc[0][3], 0, 0, 0);
      gacc[1][4] = __builtin_amdgcn_mfma_f32_16x16x32_bf16(aV[1][kb], e1, gacc[1][4], 0, 0, 0);
      gacc[0][4] = __builtin_amdgcn_mfma_f32_16x16x32_bf16(aV[0][kb], e2, gacc[0][4], 0, 0, 0);
#undef LDE
    }
    __builtin_amdgcn_s_setprio(0);

    // diag-gather G via bpermute: S[f][i,j] += G[f][i, 15-i+j(+band)]
#pragma unroll
    for (int f = 0; f < 2; ++f)
#pragma unroll
      for (int r = 0; r < 4; ++r) {
        float gsh[5];
#pragma unroll
        for (int cf = 0; cf < 5; ++cf)
          gsh[cf] = __shfl(gacc[f][cf][r], srcLn[r], 64);
#pragma unroll
        for (int nf = 0; nf < 4; ++nf)
          skacc[f][nf][r] += hiSel[r] ? gsh[nf + 1] : gsh[nf];
      }

    // online softmax in exp2 domain; reductions via DPP (VALU)
    float scl[2][4];
#pragma unroll
    for (int f = 0; f < 2; ++f) {
      float rsum[4];
#pragma unroll
      for (int r = 0; r < 4; ++r) {
        float t = fmaxf(fmaxf(skacc[f][0][r], skacc[f][1][r]),
                        fmaxf(skacc[f][2][r], skacc[f][3][r]));
        t = rowmax16(t);
        const float mnew = fmaxf(mrun[f][r], t);
        scl[f][r] = __builtin_amdgcn_exp2f(mrun[f][r] - mnew);
        mrun[f][r] = mnew;
        rsum[r] = 0.f;
      }
#pragma unroll
      for (int nf = 0; nf < 4; ++nf)
#pragma unroll
        for (int r = 0; r < 4; ++r) {
          const float p = __builtin_amdgcn_exp2f(skacc[f][nf][r] - mrun[f][r]);
          rsum[r] += p;
          const int rloc = 16 * f + ilocb + r;
          const int jb = (nf * 16 + rsel) * 2;
          *(unsigned short*)((char*)sP[wave] + rloc * 128 +
                             (jb ^ ((rloc & 7) << 4))) = f2bf(p);
        }
#pragma unroll
      for (int r = 0; r < 4; ++r)
        lrun[f][r] = lrun[f][r] * scl[f][r] + rowsum16(rsum[r]);
#pragma unroll
      for (int nf = 0; nf < 4; ++nf)
#pragma unroll
        for (int r = 0; r < 4; ++r) oacc[f][nf][r] *= scl[f][r];
    }

    // O += P@V : A-frags per i-frag from sP, B-frags shared from sVt[cur]
    __builtin_amdgcn_s_setprio(1);
#pragma unroll
    for (int kb = 0; kb < 2; ++kb) {
      const int kbyte = kb * 64 + g * 16;
      short8 ap[2];
#pragma unroll
      for (int f = 0; f < 2; ++f) {
        const int pr = 16 * f + rsel;
        ap[f] = *(const short8*)((const char*)sP[wave] + pr * 128 +
                                 (kbyte ^ ((pr & 7) << 4)));
      }
#pragma unroll
      for (int nf = 0; nf < 4; ++nf) {
        const int rv = nf * 16 + rsel;
        short8 vb8 = *(const short8*)((const char*)sVt + cur * 8192 + rv * 128 +
                                      (kbyte ^ (((rv ^ (rv >> 3)) & 7) << 4)));
#pragma unroll
        for (int f = 0; f < 2; ++f)
          oacc[f][nf] = __builtin_amdgcn_mfma_f32_16x16x32_bf16(
              ap[f], vb8, oacc[f][nf], 0, 0, 0);
      }
    }
    __builtin_amdgcn_s_setprio(0);
  }

  // epilogue
#pragma unroll
  for (int f = 0; f < 2; ++f)
#pragma unroll
    for (int nf = 0; nf < 4; ++nf)
#pragma unroll
      for (int r = 0; r < 4; ++r) {
        const int t = q0 + 32 * wave + 16 * f + ilocb + r;
        const int col = h * 64 + nf * 16 + rsel;
        O[(size_t)(b * 512 + t) * 1024 + col] = f2bf(oacc[f][nf][r] / lrun[f][r]);
      }
}

// ---------------- launch ----------------
extern "C" void kernel_launch(void* const* d_in, const int* in_sizes, int n_in,
                              void* d_out, int out_size, void* d_ws, size_t ws_size,
                              hipStream_t stream) {
  const float* x  = (const float*)d_in[0];
  const float* Wq = (const float*)d_in[1];
  const float* bq = (const float*)d_in[2];
  const float* Wk = (const float*)d_in[3];
  const float* bk = (const float*)d_in[4];
  const float* Wv = (const float*)d_in[5];
  const float* bv = (const float*)d_in[6];
  const float* Wp = (const float*)d_in[7];
  const float* bp = (const float*)d_in[8];
  const float* Wo = (const float*)d_in[9];
  const float* bo = (const float*)d_in[10];
  const float* u  = (const float*)d_in[11];
  const float* v  = (const float*)d_in[12];
  float* out = (float*)d_out;

  char* ws = (char*)d_ws;
  const size_t MB = 1024 * 1024;
  unsigned short* xb    = (unsigned short*)(ws);             // 4096x1024 bf16
  unsigned short* Wqkvb = (unsigned short*)(ws + 8 * MB);    // 3072x1024
  unsigned short* Wpb   = (unsigned short*)(ws + 14 * MB);   // 1024x1024
  unsigned short* Wob   = (unsigned short*)(ws + 16 * MB);   // 1024x1024
  unsigned short* peb   = (unsigned short*)(ws + 18 * MB);   // 1024x1024
  unsigned short* QKVb  = (unsigned short*)(ws + 20 * MB);   // 4096x3072
  unsigned short* Eb    = (unsigned short*)(ws + 44 * MB);   // 1024x1024
  unsigned short* Ob    = (unsigned short*)(ws + 46 * MB);   // 4096x1024
  float* bqkv           = (float*)(ws + 54 * MB);            // 3072 f32

  prep_kernel<<<dim3(11276), dim3(256), 0, stream>>>(
      x, Wq, Wk, Wv, Wp, Wo, bq, bk, bv, xb, Wqkvb, Wpb, Wob, peb, bqkv);

  gemm_qkv_e_kernel<<<dim3(832), dim3(256), 0, stream>>>(
      xb, Wqkvb, bqkv, QKVb, peb, Wpb, bp, Eb);
  attn_kernel<<<dim3(512), dim3(256), 0, stream>>>(QKVb, Eb, u, v, Ob);
  gemm_out_kernel<<<dim3(256), dim3(256), 0, stream>>>(Ob, Wob, bo, out);
}

// Round 12
// 111.496 us; speedup vs baseline: 1.0851x; 1.0147x over previous
//
#include <hip/hip_runtime.h>
#include <hip/hip_bf16.h>
#include <cmath>

using short8  = __attribute__((ext_vector_type(8))) short;
using f32x4   = __attribute__((ext_vector_type(4))) float;
using uint4v  = __attribute__((ext_vector_type(4))) unsigned;

#define DEV static __device__ __forceinline__

DEV unsigned short f2bf(float f) {
  union { float f; unsigned u; } v; v.f = f;
  unsigned r = v.u + 0x7FFFu + ((v.u >> 16) & 1u);
  return (unsigned short)(r >> 16);
}
DEV float bf2f(unsigned short b) {
  union { unsigned u; float f; } v; v.u = ((unsigned)b) << 16;
  return v.f;
}

DEV void async_copy16(const void* g, void* l) {
  __builtin_amdgcn_global_load_lds(
      (const __attribute__((address_space(1))) void*)g,
      (__attribute__((address_space(3))) void*)l, 16, 0, 0);
}

// DPP helpers: row_ror:N within 16-lane rows (VALU pipe, no LDS)
#define DPPF(x, ctrl)                                                     \
  __builtin_bit_cast(float, __builtin_amdgcn_update_dpp(                  \
      __builtin_bit_cast(int, (x)), __builtin_bit_cast(int, (x)), (ctrl), \
      0xF, 0xF, false))

DEV float rowmax16(float t) {
  t = fmaxf(t, DPPF(t, 0x128));
  t = fmaxf(t, DPPF(t, 0x124));
  t = fmaxf(t, DPPF(t, 0x122));
  t = fmaxf(t, DPPF(t, 0x121));
  return t;
}
DEV float rowsum16(float t) {
  t += DPPF(t, 0x128);
  t += DPPF(t, 0x124);
  t += DPPF(t, 0x122);
  t += DPPF(t, 0x121);
  return t;
}
DEV unsigned dpp_xor8(unsigned x) {  // lane^8 within each 16-lane row
  return (unsigned)__builtin_amdgcn_update_dpp((int)x, (int)x, 0x128, 0xF, 0xF, false);
}

// ---------------- fused prep: f32->bf16 converts + PE table + bias pack ----
__global__ __launch_bounds__(256) void prep_kernel(
    const float* __restrict__ x,  const float* __restrict__ Wq,
    const float* __restrict__ Wk, const float* __restrict__ Wv,
    const float* __restrict__ Wp, const float* __restrict__ Wo,
    const float* __restrict__ bq, const float* __restrict__ bk,
    const float* __restrict__ bv,
    unsigned short* __restrict__ xb, unsigned short* __restrict__ Wqkvb,
    unsigned short* __restrict__ Wpb, unsigned short* __restrict__ Wob,
    unsigned short* __restrict__ peb, float* __restrict__ bqkv) {
  const int blk = blockIdx.x;
  const int tid = threadIdx.x;
  if (blk < 9216) {  // converts
    const float* src;
    unsigned short* dst;
    int i;
    if (blk < 4096) {
      src = x; dst = xb; i = blk * 256 + tid;
    } else {
      const int w = (blk - 4096) >> 10;
      i = ((blk - 4096) & 1023) * 256 + tid;
      if      (w == 0) { src = Wq; dst = Wqkvb; }
      else if (w == 1) { src = Wk; dst = Wqkvb + 1048576; }
      else if (w == 2) { src = Wv; dst = Wqkvb + 2097152; }
      else if (w == 3) { src = Wp; dst = Wpb; }
      else             { src = Wo; dst = Wob; }
    }
    float4 v = ((const float4*)src)[i];
    ushort4 o;
    o.x = f2bf(v.x); o.y = f2bf(v.y); o.z = f2bf(v.z); o.w = f2bf(v.w);
    ((ushort4*)dst)[i] = o;
  } else if (blk < 11264) {  // PE table
    const int idx = (blk - 9216) * 256 + tid;
    const int r = idx >> 9;
    const int m = idx & 511;
    const float inv_freq = __expf((float)m * -0.017988946039016004f);
    const float ang = (float)(511 - r) * inv_freq;
    peb[(size_t)r * 1024 + 2 * m]     = f2bf(sinf(ang));
    peb[(size_t)r * 1024 + 2 * m + 1] = f2bf(cosf(ang));
  } else {  // bias pack
    const int i = (blk - 11264) * 256 + tid;
    const float* s = (i < 1024) ? bq : (i < 2048) ? bk : bv;
    bqkv[i] = s[i & 1023];
  }
}

// ---------------- GEMM tile body: C[M,N] = A[M,K] @ B[N,K]^T + bias[N] -----
// Double-buffered K-loop (one barrier/step, next-tile glds hidden under
// current compute). MFMA operands SWAPPED -> transposed fragments: lane
// holds row m=rsel, cols n=4g+r -> vectorized ushort4/float4 C stores.
template <int OUTF32>
DEV void gemm_tile(const unsigned short* __restrict__ A,
                   const unsigned short* __restrict__ B,
                   const float* __restrict__ bias, void* __restrict__ Cout,
                   int N, int K, int m0, int n0, int tid,
                   unsigned short* sA, unsigned short* sB) {
  const int lane = tid & 63;
  const int wave = tid >> 6;

  const unsigned short* gA[4];
  const unsigned short* gB[4];
  unsigned ldst[4];
#pragma unroll
  for (int it = 0; it < 4; ++it) {
    unsigned o = (unsigned)(it * 4096 + wave * 1024 + lane * 16);
    unsigned row = o >> 7;
    unsigned x = (o & 127u) ^ ((row & 7u) << 4);
    ldst[it] = it * 4096 + wave * 1024;
    gA[it] = A + (size_t)(m0 + (int)row) * K + (x >> 1);
    gB[it] = B + (size_t)(n0 + (int)row) * K + (x >> 1);
  }

  f32x4 acc[4][4];
#pragma unroll
  for (int i = 0; i < 4; ++i)
#pragma unroll
    for (int j = 0; j < 4; ++j) acc[i][j] = f32x4{0.f, 0.f, 0.f, 0.f};

  const int wm = (wave >> 1) << 6;
  const int wn = (wave & 1) << 6;
  const int rsel = lane & 15;
  const int g = lane >> 4;
  const int ksel = g << 4;

  // prologue: stage K-tile 0 into buffer 0
#pragma unroll
  for (int it = 0; it < 4; ++it) {
    async_copy16(gA[it], (char*)sA + ldst[it]);
    async_copy16(gB[it], (char*)sB + ldst[it]);
  }

  int cur = 0;
  for (int k0 = 0; k0 < K; k0 += 64) {
    __syncthreads();  // drains glds for buf[cur]; all waves done reading buf[cur^1]
    if (k0 + 64 < K) {
#pragma unroll
      for (int it = 0; it < 4; ++it) {
        async_copy16(gA[it] + k0 + 64, (char*)sA + (cur ^ 1) * 16384 + ldst[it]);
        async_copy16(gB[it] + k0 + 64, (char*)sB + (cur ^ 1) * 16384 + ldst[it]);
      }
    }
    const char* sAc = (const char*)sA + cur * 16384;
    const char* sBc = (const char*)sB + cur * 16384;
    __builtin_amdgcn_s_setprio(1);
#pragma unroll
    for (int kb = 0; kb < 2; ++kb) {
      const int kbyte = kb * 64 + ksel;
      short8 af[4], bf8[4];
#pragma unroll
      for (int i = 0; i < 4; ++i) {
        const int ra = wm + i * 16 + rsel;
        af[i] = *(const short8*)(sAc + ra * 128 + (kbyte ^ ((ra & 7) << 4)));
        const int rb = wn + i * 16 + rsel;
        bf8[i] = *(const short8*)(sBc + rb * 128 + (kbyte ^ ((rb & 7) << 4)));
      }
#pragma unroll
      for (int i = 0; i < 4; ++i)
#pragma unroll
        for (int j = 0; j < 4; ++j)
          acc[i][j] = __builtin_amdgcn_mfma_f32_16x16x32_bf16(bf8[j], af[i], acc[i][j], 0, 0, 0);
    }
    __builtin_amdgcn_s_setprio(0);
    cur ^= 1;
  }

  // epilogue: acc[i][j][r] = C[m0+wm+i*16+rsel][n0+wn+j*16+4g+r]
#pragma unroll
  for (int i = 0; i < 4; ++i) {
    const int row = m0 + wm + i * 16 + rsel;
#pragma unroll
    for (int j = 0; j < 4; ++j) {
      const int col0 = n0 + wn + j * 16 + 4 * g;
      const float4 bb = *(const float4*)(bias + col0);
      if (OUTF32) {
        float4 o;
        o.x = acc[i][j][0] + bb.x;
        o.y = acc[i][j][1] + bb.y;
        o.z = acc[i][j][2] + bb.z;
        o.w = acc[i][j][3] + bb.w;
        *(float4*)&((float*)Cout)[(size_t)row * N + col0] = o;
      } else {
        ushort4 o;
        o.x = f2bf(acc[i][j][0] + bb.x);
        o.y = f2bf(acc[i][j][1] + bb.y);
        o.z = f2bf(acc[i][j][2] + bb.z);
        o.w = f2bf(acc[i][j][3] + bb.w);
        *(ushort4*)&((unsigned short*)Cout)[(size_t)row * N + col0] = o;
      }
    }
  }
}

// fused QKV-projection + E-projection GEMM (832 blocks: 768 QKV + 64 E)
__global__ __launch_bounds__(256) void gemm_qkv_e_kernel(
    const unsigned short* __restrict__ xb, const unsigned short* __restrict__ Wqkvb,
    const float* __restrict__ bqkv, unsigned short* __restrict__ QKVb,
    const unsigned short* __restrict__ peb, const unsigned short* __restrict__ Wpb,
    const float* __restrict__ bp, unsigned short* __restrict__ Eb) {
  __shared__ unsigned short sA[2 * 128 * 64];
  __shared__ unsigned short sB[2 * 128 * 64];
  const int cpx = 104;  // 832/8
  const int bid = (blockIdx.x & 7) * cpx + (blockIdx.x >> 3);
  if (bid < 768) {
    const int mt = bid / 24, nt = bid - mt * 24;
    gemm_tile<0>(xb, Wqkvb, bqkv, QKVb, 3072, 1024, mt << 7, nt << 7,
                 threadIdx.x, sA, sB);
  } else {
    const int b2 = bid - 768;
    gemm_tile<0>(peb, Wpb, bp, Eb, 1024, 1024, (b2 >> 3) << 7, (b2 & 7) << 7,
                 threadIdx.x, sA, sB);
  }
}

// output projection (256 blocks)
__global__ __launch_bounds__(256) void gemm_out_kernel(
    const unsigned short* __restrict__ Ob, const unsigned short* __restrict__ Wob,
    const float* __restrict__ bo, float* __restrict__ out) {
  __shared__ unsigned short sA[2 * 128 * 64];
  __shared__ unsigned short sB[2 * 128 * 64];
  const int cpx = 32;  // 256/8
  const int bid = (blockIdx.x & 7) * cpx + (blockIdx.x >> 3);
  gemm_tile<1>(Ob, Wob, bo, out, 1024, 1024, (bid >> 3) << 7, (bid & 7) << 7,
               threadIdx.x, sA, sB);
}

// ---------------- fused rel-pos flash attention ----------------
// (unchanged from round 11: 512 blocks x 4 waves, 32 q-rows/wave, streamed
// operand frags, no spill)
__global__ __launch_bounds__(256, 2) void attn_kernel(
    const unsigned short* __restrict__ QKV,  // (4096, 3072): Q|K|V
    const unsigned short* __restrict__ E,    // (1024, 1024)
    const float* __restrict__ uvec, const float* __restrict__ vvec,
    unsigned short* __restrict__ O) {        // (4096, 1024)
  __shared__ unsigned short sK[2 * 4096];
  __shared__ unsigned short sE[4 * 4096];
  __shared__ unsigned short sVt[2 * 4096];
  __shared__ unsigned short sP[4][2048];

  const int tid = threadIdx.x;
  const int lane = tid & 63;
  const int wave = tid >> 6;   // 0..3
  const int cpx = gridDim.x >> 3;
  const int bid = (blockIdx.x & 7) * cpx + (blockIdx.x >> 3);
  const int qt = bid & 3;
  const int h = (bid >> 2) & 15;
  const int b = bid >> 6;
  const int q0 = qt << 7;

  const int rsel = lane & 15;
  const int g = lane >> 4;
  const int ilocb = g << 2;
  const int cb0 = 96 - 32 * wave;  // union E-band start (96 cols, 6 frags)

  const unsigned short* Qb = QKV + (size_t)b * 512 * 3072 + h * 64;
  const unsigned short* Kb = Qb + 1024;
  const unsigned short* Vb = Qb + 2048;

  const float sc = 0.125f * 1.44269504088896f;  // 1/sqrt(dh) * log2(e)

  // ---- V(0) regs first ----
  short8 v8b[2];
#pragma unroll
  for (int it = 0; it < 2; ++it) {
    const int c = it * 256 + tid;
    v8b[it] = *(const short8*)(Vb + (size_t)(c >> 3) * 3072 + ((c & 7) << 3));
  }
  // K(0) via global_load_lds
#pragma unroll
  for (int it = 0; it < 2; ++it) {
    const unsigned o = (unsigned)(it * 4096 + wave * 1024 + lane * 16);
    const unsigned row = o >> 7;
    const unsigned x = (o & 127u) ^ ((row & 7u) << 4);
    async_copy16(Kb + (size_t)row * 3072 + (x >> 1),
                 (char*)sK + it * 4096 + wave * 1024);
  }
  // E window halves H = 6-2qt .. 8-2qt into ring slots H&3
#pragma unroll
  for (int hh = 0; hh < 3; ++hh) {
    const int H = 6 - 2 * qt + hh;
#pragma unroll
    for (int it = 0; it < 2; ++it) {
      const unsigned o = (unsigned)(it * 4096 + wave * 1024 + lane * 16);
      const unsigned row = o >> 7;
      const unsigned x = (o & 127u) ^ ((row & 7u) << 4);
      async_copy16(E + (size_t)(H * 64 + (int)row) * 1024 + h * 64 + (x >> 1),
                   (char*)sE + (H & 3) * 8192 + it * 4096 + wave * 1024);
    }
  }

  // ---- Q fragments (A-layout) for both i-frags, pre-scaled ----
  short8 aU[2][2], aV[2][2];
#pragma unroll
  for (int f = 0; f < 2; ++f) {
    const int qrow = q0 + 32 * wave + 16 * f + rsel;
    const int dob = g * 8;
#pragma unroll
    for (int kb = 0; kb < 2; ++kb) {
      short8 q8 = *(const short8*)(Qb + (size_t)qrow * 3072 + kb * 32 + dob);
#pragma unroll
      for (int j = 0; j < 8; ++j) {
        const float qf = bf2f((unsigned short)q8[j]);
        aU[f][kb][j] = (short)f2bf((qf + uvec[h * 64 + kb * 32 + dob + j]) * sc);
        aV[f][kb][j] = (short)f2bf((qf + vvec[h * 64 + kb * 32 + dob + j]) * sc);
      }
    }
  }

  // transpose V(0) -> Vt[0] (DPP lane^8 exchange, b32 writes)
#pragma unroll
  for (int it = 0; it < 2; ++it) {
    const int c = it * 256 + tid;
    const int trow = c >> 3;
    const int db = (c & 7) << 3;
    const int odd = trow & 1;
    const int kp = (trow & ~1) * 2;
    const uint4v dw = __builtin_bit_cast(uint4v, v8b[it]);
#pragma unroll
    for (int p = 0; p < 4; ++p) {
      const unsigned mine = dw[p];
      const unsigned other = dpp_xor8(mine);
      const unsigned res = odd ? ((mine & 0xffff0000u) | (other >> 16))
                               : ((other << 16) | (mine & 0xffffu));
      const int d = db + 2 * p + odd;
      *(unsigned*)((char*)sVt + d * 128 + (kp ^ (((d ^ (d >> 3)) & 7) << 4))) = res;
    }
  }
  // V(1) -> regs
#pragma unroll
  for (int it = 0; it < 2; ++it) {
    const int c = it * 256 + tid;
    v8b[it] = *(const short8*)(Vb + (size_t)(64 + (c >> 3)) * 3072 + ((c & 7) << 3));
  }

  // skew-gather shuffle constants (kt- and f-invariant)
  int srcLn[4];
  bool hiSel[4];
#pragma unroll
  for (int r = 0; r < 4; ++r) {
    const int offs = 15 - (ilocb + r) + rsel;  // 0..30
    srcLn[r] = (lane & 48) | (offs & 15);
    hiSel[r] = offs >= 16;
  }

  float mrun[2][4], lrun[2][4];
  f32x4 oacc[2][4];
#pragma unroll
  for (int f = 0; f < 2; ++f)
#pragma unroll
    for (int r = 0; r < 4; ++r) { mrun[f][r] = -INFINITY; lrun[f][r] = 0.f; }
#pragma unroll
  for (int f = 0; f < 2; ++f)
#pragma unroll
    for (int n = 0; n < 4; ++n) oacc[f][n] = f32x4{0.f, 0.f, 0.f, 0.f};

  for (int kt = 0; kt < 8; ++kt) {
    const int k0 = kt << 6;
    const int cur = kt & 1;
    const int H0 = 6 - 2 * qt + kt;  // window low half index

    __syncthreads();  // single barrier: drains prefetched glds

    if (kt < 7) {
      const int kn = k0 + 64;
      // K(kt+1) -> sK[cur^1]
#pragma unroll
      for (int it = 0; it < 2; ++it) {
        const unsigned o = (unsigned)(it * 4096 + wave * 1024 + lane * 16);
        const unsigned row = o >> 7;
        const unsigned x = (o & 127u) ^ ((row & 7u) << 4);
        async_copy16(Kb + (size_t)(kn + (int)row) * 3072 + (x >> 1),
                     (char*)sK + (cur ^ 1) * 8192 + it * 4096 + wave * 1024);
      }
      // E half H0+3 -> ring slot (H0+3)&3
      {
        const int H = H0 + 3;
#pragma unroll
        for (int it = 0; it < 2; ++it) {
          const unsigned o = (unsigned)(it * 4096 + wave * 1024 + lane * 16);
          const unsigned row = o >> 7;
          const unsigned x = (o & 127u) ^ ((row & 7u) << 4);
          async_copy16(E + (size_t)(H * 64 + (int)row) * 1024 + h * 64 + (x >> 1),
                       (char*)sE + (H & 3) * 8192 + it * 4096 + wave * 1024);
        }
      }
      // transpose V(kt+1) (in v8b, complete since barrier) -> Vt[cur^1]
#pragma unroll
      for (int it = 0; it < 2; ++it) {
        const int c = it * 256 + tid;
        const int trow = c >> 3;
        const int db = (c & 7) << 3;
        const int odd = trow & 1;
        const int kp = (trow & ~1) * 2;
        const uint4v dw = __builtin_bit_cast(uint4v, v8b[it]);
#pragma unroll
        for (int p = 0; p < 4; ++p) {
          const unsigned mine = dw[p];
          const unsigned other = dpp_xor8(mine);
          const unsigned res = odd ? ((mine & 0xffff0000u) | (other >> 16))
                                   : ((other << 16) | (mine & 0xffffu));
          const int d = db + 2 * p + odd;
          *(unsigned*)((char*)sVt + (cur ^ 1) * 8192 + d * 128 +
                       (kp ^ (((d ^ (d >> 3)) & 7) << 4))) = res;
        }
      }
    }

    f32x4 skacc[2][4], gacc[2][5];
#pragma unroll
    for (int f = 0; f < 2; ++f) {
#pragma unroll
      for (int nf = 0; nf < 4; ++nf) skacc[f][nf] = f32x4{0.f, 0.f, 0.f, 0.f};
#pragma unroll
      for (int cf = 0; cf < 5; ++cf) gacc[f][cf] = f32x4{0.f, 0.f, 0.f, 0.f};
    }

    // ---- Phase 1: SK = Qu@K^T ; K frags streamed in pairs (8 VGPR live) --
    __builtin_amdgcn_s_setprio(1);
#pragma unroll
    for (int kb = 0; kb < 2; ++kb) {
      const int kbyte = kb * 64 + g * 16;
      const char* sKc = (const char*)sK + cur * 8192;
      short8 ka, kbb;
      {
        const int r0 = rsel, r1 = 16 + rsel;
        ka  = *(const short8*)(sKc + r0 * 128 + (kbyte ^ ((r0 & 7) << 4)));
        kbb = *(const short8*)(sKc + r1 * 128 + (kbyte ^ ((r1 & 7) << 4)));
      }
      skacc[0][0] = __builtin_amdgcn_mfma_f32_16x16x32_bf16(aU[0][kb], ka,  skacc[0][0], 0, 0, 0);
      skacc[1][0] = __builtin_amdgcn_mfma_f32_16x16x32_bf16(aU[1][kb], ka,  skacc[1][0], 0, 0, 0);
      skacc[0][1] = __builtin_amdgcn_mfma_f32_16x16x32_bf16(aU[0][kb], kbb, skacc[0][1], 0, 0, 0);
      skacc[1][1] = __builtin_amdgcn_mfma_f32_16x16x32_bf16(aU[1][kb], kbb, skacc[1][1], 0, 0, 0);
      {
        const int r0 = 32 + rsel, r1 = 48 + rsel;
        ka  = *(const short8*)(sKc + r0 * 128 + (kbyte ^ ((r0 & 7) << 4)));
        kbb = *(const short8*)(sKc + r1 * 128 + (kbyte ^ ((r1 & 7) << 4)));
      }
      skacc[0][2] = __builtin_amdgcn_mfma_f32_16x16x32_bf16(aU[0][kb], ka,  skacc[0][2], 0, 0, 0);
      skacc[1][2] = __builtin_amdgcn_mfma_f32_16x16x32_bf16(aU[1][kb], ka,  skacc[1][2], 0, 0, 0);
      skacc[0][3] = __builtin_amdgcn_mfma_f32_16x16x32_bf16(aU[0][kb], kbb, skacc[0][3], 0, 0, 0);
      skacc[1][3] = __builtin_amdgcn_mfma_f32_16x16x32_bf16(aU[1][kb], kbb, skacc[1][3], 0, 0, 0);
    }
    __builtin_amdgcn_sched_barrier(0);  // keep E reads out of phase 1

    // V(kt+2) -> regs (issued here: hides under phase 2, shortens live range)
    if (kt < 6) {
#pragma unroll
      for (int it = 0; it < 2; ++it) {
        const int c = it * 256 + tid;
        v8b[it] = *(const short8*)(Vb + (size_t)(k0 + 128 + (c >> 3)) * 3072 +
                                   ((c & 7) << 3));
      }
    }

    // ---- Phase 2: G = Qv@Ewin^T ; E frags streamed in triples (12 VGPR) --
    // gacc[f][j] consumes e[j+1-f]
#pragma unroll
    for (int kb = 0; kb < 2; ++kb) {
      const int kbyte = kb * 64 + g * 16;
      short8 e0, e1, e2;
#define LDE(cfu)                                                              \
  ({                                                                          \
    const int rowbase = cb0 + 16 * (cfu);                                     \
    const int rb = rowbase + rsel;                                            \
    const int slot = (H0 + (rowbase >> 6)) & 3;                               \
    *(const short8*)((const char*)sE + slot * 8192 + (rb & 63) * 128 +        \
                     (kbyte ^ ((rb & 7) << 4)));                              \
  })
      e0 = LDE(0); e1 = LDE(1); e2 = LDE(2);
      gacc[1][0] = __builtin_amdgcn_mfma_f32_16x16x32_bf16(aV[1][kb], e0, gacc[1][0], 0, 0, 0);
      gacc[0][0] = __builtin_amdgcn_mfma_f32_16x16x32_bf16(aV[0][kb], e1, gacc[0][0], 0, 0, 0);
      gacc[1][1] = __builtin_amdgcn_mfma_f32_16x16x32_bf16(aV[1][kb], e1, gacc[1][1], 0, 0, 0);
      gacc[0][1] = __builtin_amdgcn_mfma_f32_16x16x32_bf16(aV[0][kb], e2, gacc[0][1], 0, 0, 0);
      gacc[1][2] = __builtin_amdgcn_mfma_f32_16x16x32_bf16(aV[1][kb], e2, gacc[1][2], 0, 0, 0);
      e0 = LDE(3); e1 = LDE(4); e2 = LDE(5);
      gacc[0][2] = __builtin_amdgcn_mfma_f32_16x16x32_bf16(aV[0][kb], e0, gacc[0][2], 0, 0, 0);
      gacc[1][3] = __builtin_amdgcn_mfma_f32_16x16x32_bf16(aV[1][kb], e0, gacc[1][3], 0, 0, 0);
      gacc[0][3] = __builtin_amdgcn_mfma_f32_16x16x32_bf16(aV[0][kb], e1, gacc[0][3], 0, 0, 0);
      gacc[1][4] = __builtin_amdgcn_mfma_f32_16x16x32_bf16(aV[1][kb], e1, gacc[1][4], 0, 0, 0);
      gacc[0][4] = __builtin_amdgcn_mfma_f32_16x16x32_bf16(aV[0][kb], e2, gacc[0][4], 0, 0, 0);
#undef LDE
    }
    __builtin_amdgcn_s_setprio(0);

    // diag-gather G via bpermute: S[f][i,j] += G[f][i, 15-i+j(+band)]
#pragma unroll
    for (int f = 0; f < 2; ++f)
#pragma unroll
      for (int r = 0; r < 4; ++r) {
        float gsh[5];
#pragma unroll
        for (int cf = 0; cf < 5; ++cf)
          gsh[cf] = __shfl(gacc[f][cf][r], srcLn[r], 64);
#pragma unroll
        for (int nf = 0; nf < 4; ++nf)
          skacc[f][nf][r] += hiSel[r] ? gsh[nf + 1] : gsh[nf];
      }

    // online softmax in exp2 domain; reductions via DPP (VALU)
    float scl[2][4];
#pragma unroll
    for (int f = 0; f < 2; ++f) {
      float rsum[4];
#pragma unroll
      for (int r = 0; r < 4; ++r) {
        float t = fmaxf(fmaxf(skacc[f][0][r], skacc[f][1][r]),
                        fmaxf(skacc[f][2][r], skacc[f][3][r]));
        t = rowmax16(t);
        const float mnew = fmaxf(mrun[f][r], t);
        scl[f][r] = __builtin_amdgcn_exp2f(mrun[f][r] - mnew);
        mrun[f][r] = mnew;
        rsum[r] = 0.f;
      }
#pragma unroll
      for (int nf = 0; nf < 4; ++nf)
#pragma unroll
        for (int r = 0; r < 4; ++r) {
          const float p = __builtin_amdgcn_exp2f(skacc[f][nf][r] - mrun[f][r]);
          rsum[r] += p;
          const int rloc = 16 * f + ilocb + r;
          const int jb = (nf * 16 + rsel) * 2;
          *(unsigned short*)((char*)sP[wave] + rloc * 128 +
                             (jb ^ ((rloc & 7) << 4))) = f2bf(p);
        }
#pragma unroll
      for (int r = 0; r < 4; ++r)
        lrun[f][r] = lrun[f][r] * scl[f][r] + rowsum16(rsum[r]);
#pragma unroll
      for (int nf = 0; nf < 4; ++nf)
#pragma unroll
        for (int r = 0; r < 4; ++r) oacc[f][nf][r] *= scl[f][r];
    }

    // O += P@V : A-frags per i-frag from sP, B-frags shared from sVt[cur]
    __builtin_amdgcn_s_setprio(1);
#pragma unroll
    for (int kb = 0; kb < 2; ++kb) {
      const int kbyte = kb * 64 + g * 16;
      short8 ap[2];
#pragma unroll
      for (int f = 0; f < 2; ++f) {
        const int pr = 16 * f + rsel;
        ap[f] = *(const short8*)((const char*)sP[wave] + pr * 128 +
                                 (kbyte ^ ((pr & 7) << 4)));
      }
#pragma unroll
      for (int nf = 0; nf < 4; ++nf) {
        const int rv = nf * 16 + rsel;
        short8 vb8 = *(const short8*)((const char*)sVt + cur * 8192 + rv * 128 +
                                      (kbyte ^ (((rv ^ (rv >> 3)) & 7) << 4)));
#pragma unroll
        for (int f = 0; f < 2; ++f)
          oacc[f][nf] = __builtin_amdgcn_mfma_f32_16x16x32_bf16(
              ap[f], vb8, oacc[f][nf], 0, 0, 0);
      }
    }
    __builtin_amdgcn_s_setprio(0);
  }

  // epilogue
#pragma unroll
  for (int f = 0; f < 2; ++f)
#pragma unroll
    for (int nf = 0; nf < 4; ++nf)
#pragma unroll
      for (int r = 0; r < 4; ++r) {
        const int t = q0 + 32 * wave + 16 * f + ilocb + r;
        const int col = h * 64 + nf * 16 + rsel;
        O[(size_t)(b * 512 + t) * 1024 + col] = f2bf(oacc[f][nf][r] / lrun[f][r]);
      }
}

// ---------------- launch ----------------
extern "C" void kernel_launch(void* const* d_in, const int* in_sizes, int n_in,
                              void* d_out, int out_size, void* d_ws, size_t ws_size,
                              hipStream_t stream) {
  const float* x  = (const float*)d_in[0];
  const float* Wq = (const float*)d_in[1];
  const float* bq = (const float*)d_in[2];
  const float* Wk = (const float*)d_in[3];
  const float* bk = (const float*)d_in[4];
  const float* Wv = (const float*)d_in[5];
  const float* bv = (const float*)d_in[6];
  const float* Wp = (const float*)d_in[7];
  const float* bp = (const float*)d_in[8];
  const float* Wo = (const float*)d_in[9];
  const float* bo = (const float*)d_in[10];
  const float* u  = (const float*)d_in[11];
  const float* v  = (const float*)d_in[12];
  float* out = (float*)d_out;

  char* ws = (char*)d_ws;
  const size_t MB = 1024 * 1024;
  unsigned short* xb    = (unsigned short*)(ws);             // 4096x1024 bf16
  unsigned short* Wqkvb = (unsigned short*)(ws + 8 * MB);    // 3072x1024
  unsigned short* Wpb   = (unsigned short*)(ws + 14 * MB);   // 1024x1024
  unsigned short* Wob   = (unsigned short*)(ws + 16 * MB);   // 1024x1024
  unsigned short* peb   = (unsigned short*)(ws + 18 * MB);   // 1024x1024
  unsigned short* QKVb  = (unsigned short*)(ws + 20 * MB);   // 4096x3072
  unsigned short* Eb    = (unsigned short*)(ws + 44 * MB);   // 1024x1024
  unsigned short* Ob    = (unsigned short*)(ws + 46 * MB);   // 4096x1024
  float* bqkv           = (float*)(ws + 54 * MB);            // 3072 f32

  prep_kernel<<<dim3(11276), dim3(256), 0, stream>>>(
      x, Wq, Wk, Wv, Wp, Wo, bq, bk, bv, xb, Wqkvb, Wpb, Wob, peb, bqkv);

  gemm_qkv_e_kernel<<<dim3(832), dim3(256), 0, stream>>>(
      xb, Wqkvb, bqkv, QKVb, peb, Wpb, bp, Eb);
  attn_kernel<<<dim3(512), dim3(256), 0, stream>>>(QKVb, Eb, u, v, Ob);
  gemm_out_kernel<<<dim3(256), dim3(256), 0, stream>>>(Ob, Wob, bo, out);
}